// Round 1
// baseline (4141.771 us; speedup 1.0000x reference)
//
#include <hip/hip_runtime.h>
#include <math.h>

#define DD 128
#define CC 16
#define ALPHA_ 0.5f
#define EPS_LN 1e-5f
#define EPS_COS 1e-8f

// ---------------- Kernel A: feature transform (Linear->LN->ReLU->L2norm) ----
// block 256: j = tid&127 (output col), sg = tid>>7 (row subgroup), 16 rows/iter.
// W staged in LDS as float4 chunks, XOR-swizzled so the strided read
// (fixed chunk, j varying) is bank-conflict-free. feat reads are uniform
// broadcasts per wave.
__global__ __launch_bounds__(256, 2) void ft_kernel(
    const float* __restrict__ feat, const float* __restrict__ W,
    const float* __restrict__ b, const float* __restrict__ gamma,
    const float* __restrict__ beta, float* __restrict__ hn, int N)
{
    __shared__ float4 Wl[128 * 32];
    __shared__ float4 Fl[16 * 32];
    __shared__ float red[4][8][2];

    const int tid = threadIdx.x;
    const int j   = tid & 127;
    const int sg  = tid >> 7;
    const int wid = tid >> 6;
    const int swz = (j >> 3) & 7;

    // stage W (64 KB), swizzled: chunk c of row jj stored at slot c ^ s(jj)
    const float4* Wg = (const float4*)W;
    for (int idx = tid; idx < 128 * 32; idx += 256) {
        int jj = idx >> 5, c = idx & 31;
        Wl[jj * 32 + (c ^ ((jj >> 3) & 7))] = Wg[idx];
    }
    const float bj = b[j], gj = gamma[j], bej = beta[j];
    __syncthreads();

    const int iters = (N + 15) >> 4;
    for (int g = blockIdx.x; g < iters; g += gridDim.x) {
        const int row0 = g << 4;
        __syncthreads();  // previous iteration fully done before Fl overwrite
        for (int idx = tid; idx < 16 * 32; idx += 256) {
            int r = idx >> 5;
            int grow = row0 + r;
            Fl[idx] = (grow < N) ? ((const float4*)feat)[(size_t)grow * 32 + (idx & 31)]
                                 : make_float4(0.f, 0.f, 0.f, 0.f);
        }
        __syncthreads();

        float acc[8];
#pragma unroll
        for (int r = 0; r < 8; ++r) acc[r] = bj;
#pragma unroll
        for (int cc2 = 0; cc2 < 32; ++cc2) {
            float4 w4 = Wl[j * 32 + (cc2 ^ swz)];   // retrieves chunk cc2 of W[j]
#pragma unroll
            for (int r = 0; r < 8; ++r) {
                float4 f4 = Fl[(sg * 8 + r) * 32 + cc2];  // uniform per wave
                acc[r] += w4.x * f4.x + w4.y * f4.y + w4.z * f4.z + w4.w * f4.w;
            }
        }

        // ---- LayerNorm: mean/var across the 128 cols (2 waves per sg) ----
#pragma unroll
        for (int r = 0; r < 8; ++r) {
            float s = acc[r], s2 = acc[r] * acc[r];
#pragma unroll
            for (int m = 1; m <= 32; m <<= 1) {
                s  += __shfl_xor(s, m);
                s2 += __shfl_xor(s2, m);
            }
            if ((tid & 63) == 0) { red[wid][r][0] = s; red[wid][r][1] = s2; }
        }
        __syncthreads();
        float v[8];
#pragma unroll
        for (int r = 0; r < 8; ++r) {
            float s  = red[sg * 2][r][0] + red[sg * 2 + 1][r][0];
            float s2 = red[sg * 2][r][1] + red[sg * 2 + 1][r][1];
            float mu  = s * (1.f / 128.f);
            float var = s2 * (1.f / 128.f) - mu * mu;
            float rstd = rsqrtf(var + EPS_LN);
            float x = (acc[r] - mu) * rstd * gj + bej;
            v[r] = fmaxf(x, 0.f);
        }
        __syncthreads();  // phase-1 reads of red done before phase-2 writes
#pragma unroll
        for (int r = 0; r < 8; ++r) {
            float s = v[r] * v[r];
#pragma unroll
            for (int m = 1; m <= 32; m <<= 1) s += __shfl_xor(s, m);
            if ((tid & 63) == 0) red[wid][r][0] = s;
        }
        __syncthreads();
#pragma unroll
        for (int r = 0; r < 8; ++r) {
            float nsq = red[sg * 2][r][0] + red[sg * 2 + 1][r][0];
            float nrm = fmaxf(sqrtf(nsq), EPS_COS);
            int grow = row0 + sg * 8 + r;
            if (grow < N) hn[(size_t)grow * 128 + j] = v[r] / nrm;
        }
    }
}

// ---------------- Kernel B: per-edge weight = sigmoid(ew)*cos(src,dst) ------
// 32 lanes per edge, float4 per lane, shfl reduce within the 32-lane group.
__global__ void sim_kernel(const float* __restrict__ hn,
    const int* __restrict__ s0, const int* __restrict__ d0,
    const int* __restrict__ s1, const int* __restrict__ d1,
    const int* __restrict__ s2, const int* __restrict__ d2,
    const float* __restrict__ ew0, const float* __restrict__ ew1,
    const float* __restrict__ ew2,
    float* __restrict__ w_all, float* __restrict__ total_w, int E)
{
    const int gtid = blockIdx.x * blockDim.x + threadIdx.x;
    const int lane = gtid & 31;
    const int grp  = gtid >> 5;
    const int ngrp = (gridDim.x * blockDim.x) >> 5;
    const int tot = 3 * E;
    const float4* hn4 = (const float4*)hn;
    for (int e = grp; e < tot; e += ngrp) {
        const int* sp; const int* dp; int le; float ew;
        if (e < E)          { le = e;         sp = s0; dp = d0; ew = ew0[0]; }
        else if (e < 2 * E) { le = e - E;     sp = s1; dp = d1; ew = ew1[0]; }
        else                { le = e - 2 * E; sp = s2; dp = d2; ew = ew2[0]; }
        int src = sp[le], dst = dp[le];
        float4 a = hn4[(size_t)src * 32 + lane];
        float4 c = hn4[(size_t)dst * 32 + lane];
        float p = a.x * c.x + a.y * c.y + a.z * c.z + a.w * c.w;
#pragma unroll
        for (int m = 1; m <= 16; m <<= 1) p += __shfl_xor(p, m);
        if (lane == 0) {
            float w = (1.f / (1.f + expf(-ew))) * p;
            w_all[e] = w;
            atomicAdd(&total_w[src], w);
        }
    }
}

// ---------------- Kernel C: per-node scale = total>0 ? 1/total : 1 ----------
__global__ void scale_kernel(const float* __restrict__ total_w,
                             float* __restrict__ scl, int N)
{
    int i = blockIdx.x * blockDim.x + threadIdx.x;
    int stride = gridDim.x * blockDim.x;
    for (; i < N; i += stride) {
        float t = total_w[i];
        scl[i] = (t > 0.f) ? 1.f / t : 1.f;
    }
}

// ---------------- Kernel D1: scatter next[src] += w * cur[dst] --------------
// 16 lanes per edge (one per class).
__global__ void scatter_kernel(const float* __restrict__ w_all,
    const float* __restrict__ cur,
    const int* __restrict__ s0, const int* __restrict__ d0,
    const int* __restrict__ s1, const int* __restrict__ d1,
    const int* __restrict__ s2, const int* __restrict__ d2,
    float* __restrict__ nxt, int E)
{
    const int gtid = blockIdx.x * blockDim.x + threadIdx.x;
    const int c    = gtid & 15;
    const int grp  = gtid >> 4;
    const int ngrp = (gridDim.x * blockDim.x) >> 4;
    const int tot = 3 * E;
    for (int e = grp; e < tot; e += ngrp) {
        const int* sp; const int* dp; int le;
        if (e < E)          { le = e;         sp = s0; dp = d0; }
        else if (e < 2 * E) { le = e - E;     sp = s1; dp = d1; }
        else                { le = e - 2 * E; sp = s2; dp = d2; }
        float w = w_all[e];
        int src = sp[le], dst = dp[le];
        atomicAdd(&nxt[(size_t)src * 16 + c], w * cur[(size_t)dst * 16 + c]);
    }
}

// ---------------- Kernel D2: cur = ALPHA*scale*next + (1-ALPHA)*init --------
__global__ void finalize_kernel(const float* __restrict__ nxt,
    const float* __restrict__ scl, const float* __restrict__ init,
    float* __restrict__ out, int NC)
{
    int i = blockIdx.x * blockDim.x + threadIdx.x;
    int stride = gridDim.x * blockDim.x;
    for (; i < NC; i += stride) {
        int n = i >> 4;
        out[i] = ALPHA_ * nxt[i] * scl[n] + (1.f - ALPHA_) * init[i];
    }
}

extern "C" void kernel_launch(void* const* d_in, const int* in_sizes, int n_in,
                              void* d_out, int out_size, void* d_ws, size_t ws_size,
                              hipStream_t stream)
{
    const float* feat  = (const float*)d_in[0];
    const float* initl = (const float*)d_in[1];
    const float* W     = (const float*)d_in[2];
    const float* b     = (const float*)d_in[3];
    const float* gam   = (const float*)d_in[4];
    const float* bet   = (const float*)d_in[5];
    const float* ew0   = (const float*)d_in[6];
    const float* ew1   = (const float*)d_in[7];
    const float* ew2   = (const float*)d_in[8];
    const int* s0 = (const int*)d_in[9];
    const int* dd0 = (const int*)d_in[10];
    const int* s1 = (const int*)d_in[11];
    const int* dd1 = (const int*)d_in[12];
    const int* s2 = (const int*)d_in[13];
    const int* dd2 = (const int*)d_in[14];

    const int N = in_sizes[0] / DD;
    const int E = in_sizes[9];
    float* out = (float*)d_out;

    char* ws = (char*)d_ws;
    size_t off = 0;
    auto alloc = [&](size_t bytes) -> void* {
        void* p = ws + off;
        off += (bytes + 255) & ~(size_t)255;
        return p;
    };
    float* hn      = (float*)alloc((size_t)N * DD * 4);
    float* w_all   = (float*)alloc((size_t)3 * E * 4);
    float* total_w = (float*)alloc((size_t)N * 4);
    float* scl     = (float*)alloc((size_t)N * 4);
    float* nxt     = (float*)alloc((size_t)N * CC * 4);
    float* cur     = (float*)alloc((size_t)N * CC * 4);

    // 1) feature transform -> hn
    ft_kernel<<<512, 256, 0, stream>>>(feat, W, b, gam, bet, hn, N);

    // 2) edge weights + per-node totals
    hipMemsetAsync(total_w, 0, (size_t)N * 4, stream);
    sim_kernel<<<2048, 256, 0, stream>>>(hn, s0, dd0, s1, dd1, s2, dd2,
                                         ew0, ew1, ew2, w_all, total_w, E);
    scale_kernel<<<256, 256, 0, stream>>>(total_w, scl, N);

    // 3) 5 propagation layers
    const float* cs = initl;
    for (int layer = 0; layer < 5; ++layer) {
        hipMemsetAsync(nxt, 0, (size_t)N * CC * 4, stream);
        scatter_kernel<<<2048, 256, 0, stream>>>(w_all, cs, s0, dd0, s1, dd1,
                                                 s2, dd2, nxt, E);
        float* dst = (layer == 4) ? out : cur;
        finalize_kernel<<<2048, 256, 0, stream>>>(nxt, scl, initl, dst, N * CC);
        cs = cur;
    }
}

// Round 2
// 1358.771 us; speedup vs baseline: 3.0482x; 3.0482x over previous
//
#include <hip/hip_runtime.h>
#include <math.h>

#define DD 128
#define CC 16
#define ALPHA_ 0.5f
#define EPS_LN 1e-5f
#define EPS_COS 1e-8f

// ---------------- Kernel A: feature transform (Linear->LN->ReLU->L2norm) ----
// block 256 = 8 row-groups x 32 col-quads. Tile: 32 rows x 128 cols.
// Each thread: acc[4 rows][4 cols], statically indexed (no scratch).
// W in LDS (64 KB), chunk kc of row r stored at slot kc ^ ((r>>2)&31) so the
// 32-lane read (rows 4*jq+i, fixed kc) covers all 32 banks -> conflict-free.
// LN and L2-norm via __shfl_xor within each 32-lane row-group; no LDS reds.
__global__ __launch_bounds__(256, 2) void ft_kernel(
    const float* __restrict__ feat, const float* __restrict__ W,
    const float* __restrict__ b, const float* __restrict__ gamma,
    const float* __restrict__ beta, float* __restrict__ hn, int N)
{
    __shared__ float4 Wl[128 * 32];   // 64 KB
    __shared__ float4 Fl[32 * 32];    // 16 KB

    const int tid = threadIdx.x;
    const int jq  = tid & 31;   // col quad: cols 4*jq .. 4*jq+3
    const int rq  = tid >> 5;   // row group: rows 4*rq .. 4*rq+3 of tile

    // stage W swizzled (coalesced float4 reads)
    const float4* Wg = (const float4*)W;
    for (int idx = tid; idx < 128 * 32; idx += 256) {
        int r = idx >> 5, kc = idx & 31;
        Wl[r * 32 + (kc ^ ((r >> 2) & 31))] = Wg[idx];
    }
    // per-thread column constants
    const float4 b4  = ((const float4*)b)[jq];
    const float4 g4  = ((const float4*)gamma)[jq];
    const float4 be4 = ((const float4*)beta)[jq];
    __syncthreads();

    const int iters = (N + 31) >> 5;
    for (int g = blockIdx.x; g < iters; g += gridDim.x) {
        const int row0 = g << 5;
        // stage 32 rows of feat (zero-padded at tail)
        for (int t = 0; t < 4; ++t) {
            int idx = tid + t * 256;            // 0..1023
            int r = idx >> 5;
            int grow = row0 + r;
            Fl[idx] = (grow < N) ? ((const float4*)feat)[(size_t)grow * 32 + (idx & 31)]
                                 : make_float4(0.f, 0.f, 0.f, 0.f);
        }
        __syncthreads();

        float acc[4][4];
#pragma unroll
        for (int r = 0; r < 4; ++r) {
            acc[r][0] = b4.x; acc[r][1] = b4.y; acc[r][2] = b4.z; acc[r][3] = b4.w;
        }

#pragma unroll 2
        for (int kc = 0; kc < 32; ++kc) {
            float4 wv[4], fv[4];
#pragma unroll
            for (int i = 0; i < 4; ++i)
                wv[i] = Wl[(4 * jq + i) * 32 + (kc ^ jq)];
#pragma unroll
            for (int i = 0; i < 4; ++i)
                fv[i] = Fl[(4 * rq + i) * 32 + kc];
#pragma unroll
            for (int r = 0; r < 4; ++r) {
#pragma unroll
                for (int c = 0; c < 4; ++c) {
                    acc[r][c] += fv[r].x * wv[c].x + fv[r].y * wv[c].y
                               + fv[r].z * wv[c].z + fv[r].w * wv[c].w;
                }
            }
        }
        __syncthreads();  // k-loop reads done before next-iter Fl overwrite

        // ---- LayerNorm + ReLU + L2-normalize, per row (reduce over 32 lanes)
#pragma unroll
        for (int r = 0; r < 4; ++r) {
            float s  = acc[r][0] + acc[r][1] + acc[r][2] + acc[r][3];
            float s2 = acc[r][0] * acc[r][0] + acc[r][1] * acc[r][1]
                     + acc[r][2] * acc[r][2] + acc[r][3] * acc[r][3];
#pragma unroll
            for (int m = 1; m <= 16; m <<= 1) {
                s  += __shfl_xor(s, m);
                s2 += __shfl_xor(s2, m);
            }
            float mu   = s * (1.f / 128.f);
            float var  = s2 * (1.f / 128.f) - mu * mu;
            float rstd = rsqrtf(var + EPS_LN);

            float v0 = fmaxf((acc[r][0] - mu) * rstd * g4.x + be4.x, 0.f);
            float v1 = fmaxf((acc[r][1] - mu) * rstd * g4.y + be4.y, 0.f);
            float v2 = fmaxf((acc[r][2] - mu) * rstd * g4.z + be4.z, 0.f);
            float v3 = fmaxf((acc[r][3] - mu) * rstd * g4.w + be4.w, 0.f);

            float nsq = v0 * v0 + v1 * v1 + v2 * v2 + v3 * v3;
#pragma unroll
            for (int m = 1; m <= 16; m <<= 1) nsq += __shfl_xor(nsq, m);
            float inv = 1.f / fmaxf(sqrtf(nsq), EPS_COS);

            int grow = row0 + 4 * rq + r;
            if (grow < N) {
                float4 st = make_float4(v0 * inv, v1 * inv, v2 * inv, v3 * inv);
                ((float4*)hn)[(size_t)grow * 32 + jq] = st;
            }
        }
    }
}

// ---------------- Kernel B: per-edge weight = sigmoid(ew)*cos(src,dst) ------
// 32 lanes per edge, float4 per lane, shfl reduce within the 32-lane group.
__global__ void sim_kernel(const float* __restrict__ hn,
    const int* __restrict__ s0, const int* __restrict__ d0,
    const int* __restrict__ s1, const int* __restrict__ d1,
    const int* __restrict__ s2, const int* __restrict__ d2,
    const float* __restrict__ ew0, const float* __restrict__ ew1,
    const float* __restrict__ ew2,
    float* __restrict__ w_all, float* __restrict__ total_w, int E)
{
    const int gtid = blockIdx.x * blockDim.x + threadIdx.x;
    const int lane = gtid & 31;
    const int grp  = gtid >> 5;
    const int ngrp = (gridDim.x * blockDim.x) >> 5;
    const int tot = 3 * E;
    const float4* hn4 = (const float4*)hn;
    for (int e = grp; e < tot; e += ngrp) {
        const int* sp; const int* dp; int le; float ew;
        if (e < E)          { le = e;         sp = s0; dp = d0; ew = ew0[0]; }
        else if (e < 2 * E) { le = e - E;     sp = s1; dp = d1; ew = ew1[0]; }
        else                { le = e - 2 * E; sp = s2; dp = d2; ew = ew2[0]; }
        int src = sp[le], dst = dp[le];
        float4 a = hn4[(size_t)src * 32 + lane];
        float4 c = hn4[(size_t)dst * 32 + lane];
        float p = a.x * c.x + a.y * c.y + a.z * c.z + a.w * c.w;
#pragma unroll
        for (int m = 1; m <= 16; m <<= 1) p += __shfl_xor(p, m);
        if (lane == 0) {
            float w = (1.f / (1.f + expf(-ew))) * p;
            w_all[e] = w;
            atomicAdd(&total_w[src], w);
        }
    }
}

// ---------------- Kernel C: per-node scale = total>0 ? 1/total : 1 ----------
__global__ void scale_kernel(const float* __restrict__ total_w,
                             float* __restrict__ scl, int N)
{
    int i = blockIdx.x * blockDim.x + threadIdx.x;
    int stride = gridDim.x * blockDim.x;
    for (; i < N; i += stride) {
        float t = total_w[i];
        scl[i] = (t > 0.f) ? 1.f / t : 1.f;
    }
}

// ---------------- Kernel D1: scatter next[src] += w * cur[dst] --------------
// 16 lanes per edge (one per class).
__global__ void scatter_kernel(const float* __restrict__ w_all,
    const float* __restrict__ cur,
    const int* __restrict__ s0, const int* __restrict__ d0,
    const int* __restrict__ s1, const int* __restrict__ d1,
    const int* __restrict__ s2, const int* __restrict__ d2,
    float* __restrict__ nxt, int E)
{
    const int gtid = blockIdx.x * blockDim.x + threadIdx.x;
    const int c    = gtid & 15;
    const int grp  = gtid >> 4;
    const int ngrp = (gridDim.x * blockDim.x) >> 4;
    const int tot = 3 * E;
    for (int e = grp; e < tot; e += ngrp) {
        const int* sp; const int* dp; int le;
        if (e < E)          { le = e;         sp = s0; dp = d0; }
        else if (e < 2 * E) { le = e - E;     sp = s1; dp = d1; }
        else                { le = e - 2 * E; sp = s2; dp = d2; }
        float w = w_all[e];
        int src = sp[le], dst = dp[le];
        atomicAdd(&nxt[(size_t)src * 16 + c], w * cur[(size_t)dst * 16 + c]);
    }
}

// ---------------- Kernel D2: cur = ALPHA*scale*next + (1-ALPHA)*init --------
__global__ void finalize_kernel(const float* __restrict__ nxt,
    const float* __restrict__ scl, const float* __restrict__ init,
    float* __restrict__ out, int NC)
{
    int i = blockIdx.x * blockDim.x + threadIdx.x;
    int stride = gridDim.x * blockDim.x;
    for (; i < NC; i += stride) {
        int n = i >> 4;
        out[i] = ALPHA_ * nxt[i] * scl[n] + (1.f - ALPHA_) * init[i];
    }
}

extern "C" void kernel_launch(void* const* d_in, const int* in_sizes, int n_in,
                              void* d_out, int out_size, void* d_ws, size_t ws_size,
                              hipStream_t stream)
{
    const float* feat  = (const float*)d_in[0];
    const float* initl = (const float*)d_in[1];
    const float* W     = (const float*)d_in[2];
    const float* b     = (const float*)d_in[3];
    const float* gam   = (const float*)d_in[4];
    const float* bet   = (const float*)d_in[5];
    const float* ew0   = (const float*)d_in[6];
    const float* ew1   = (const float*)d_in[7];
    const float* ew2   = (const float*)d_in[8];
    const int* s0 = (const int*)d_in[9];
    const int* dd0 = (const int*)d_in[10];
    const int* s1 = (const int*)d_in[11];
    const int* dd1 = (const int*)d_in[12];
    const int* s2 = (const int*)d_in[13];
    const int* dd2 = (const int*)d_in[14];

    const int N = in_sizes[0] / DD;
    const int E = in_sizes[9];
    float* out = (float*)d_out;

    char* ws = (char*)d_ws;
    size_t off = 0;
    auto alloc = [&](size_t bytes) -> void* {
        void* p = ws + off;
        off += (bytes + 255) & ~(size_t)255;
        return p;
    };
    float* hn      = (float*)alloc((size_t)N * DD * 4);
    float* w_all   = (float*)alloc((size_t)3 * E * 4);
    float* total_w = (float*)alloc((size_t)N * 4);
    float* scl     = (float*)alloc((size_t)N * 4);
    float* nxt     = (float*)alloc((size_t)N * CC * 4);
    float* cur     = (float*)alloc((size_t)N * CC * 4);

    // 1) feature transform -> hn
    ft_kernel<<<512, 256, 0, stream>>>(feat, W, b, gam, bet, hn, N);

    // 2) edge weights + per-node totals
    hipMemsetAsync(total_w, 0, (size_t)N * 4, stream);
    sim_kernel<<<2048, 256, 0, stream>>>(hn, s0, dd0, s1, dd1, s2, dd2,
                                         ew0, ew1, ew2, w_all, total_w, E);
    scale_kernel<<<256, 256, 0, stream>>>(total_w, scl, N);

    // 3) 5 propagation layers
    const float* cs = initl;
    for (int layer = 0; layer < 5; ++layer) {
        hipMemsetAsync(nxt, 0, (size_t)N * CC * 4, stream);
        scatter_kernel<<<2048, 256, 0, stream>>>(w_all, cs, s0, dd0, s1, dd1,
                                                 s2, dd2, nxt, E);
        float* dst = (layer == 4) ? out : cur;
        finalize_kernel<<<2048, 256, 0, stream>>>(nxt, scl, initl, dst, N * CC);
        cs = cur;
    }
}

// Round 3
// 1089.863 us; speedup vs baseline: 3.8003x; 1.2467x over previous
//
#include <hip/hip_runtime.h>
#include <math.h>

#define DD 128
#define CC 16
#define ALPHA_ 0.5f
#define EPS_LN 1e-5f
#define EPS_COS 1e-8f

typedef __attribute__((ext_vector_type(8))) unsigned short us8;
typedef __attribute__((ext_vector_type(4))) unsigned short us4;

__device__ __forceinline__ unsigned short f2bf(float x) {
    unsigned u = __float_as_uint(x);
    u += 0x7FFFu + ((u >> 16) & 1u);   // RNE
    return (unsigned short)(u >> 16);
}
__device__ __forceinline__ float bf2f(unsigned short v) {
    return __uint_as_float((unsigned)v << 16);
}

// ---------------- Kernel A: feature transform -> bf16 L2-normalized rows ----
// block 256 = 8 row-groups x 32 col-quads. Tile: 32 rows x 128 cols.
// Each thread: acc[4][4] statically indexed. W staged in LDS, XOR-swizzled
// (kc ^ jq) so the 32-lane column-slice read covers all 32 banks.
__global__ __launch_bounds__(256, 2) void ft_kernel(
    const float* __restrict__ feat, const float* __restrict__ W,
    const float* __restrict__ b, const float* __restrict__ gamma,
    const float* __restrict__ beta, unsigned short* __restrict__ hnb, int N)
{
    __shared__ float4 Wl[128 * 32];   // 64 KB
    __shared__ float4 Fl[32 * 32];    // 16 KB

    const int tid = threadIdx.x;
    const int jq  = tid & 31;   // col quad: cols 4*jq .. 4*jq+3
    const int rq  = tid >> 5;   // row group: rows 4*rq .. 4*rq+3 of tile

    const float4* Wg = (const float4*)W;
    for (int idx = tid; idx < 128 * 32; idx += 256) {
        int r = idx >> 5, kc = idx & 31;
        Wl[r * 32 + (kc ^ ((r >> 2) & 31))] = Wg[idx];
    }
    const float4 b4  = ((const float4*)b)[jq];
    const float4 g4  = ((const float4*)gamma)[jq];
    const float4 be4 = ((const float4*)beta)[jq];
    __syncthreads();

    const int iters = (N + 31) >> 5;
    for (int g = blockIdx.x; g < iters; g += gridDim.x) {
        const int row0 = g << 5;
        for (int t = 0; t < 4; ++t) {
            int idx = tid + t * 256;
            int r = idx >> 5;
            int grow = row0 + r;
            Fl[idx] = (grow < N) ? ((const float4*)feat)[(size_t)grow * 32 + (idx & 31)]
                                 : make_float4(0.f, 0.f, 0.f, 0.f);
        }
        __syncthreads();

        float acc[4][4];
#pragma unroll
        for (int r = 0; r < 4; ++r) {
            acc[r][0] = b4.x; acc[r][1] = b4.y; acc[r][2] = b4.z; acc[r][3] = b4.w;
        }
#pragma unroll 2
        for (int kc = 0; kc < 32; ++kc) {
            float4 wv[4], fv[4];
#pragma unroll
            for (int i = 0; i < 4; ++i)
                wv[i] = Wl[(4 * jq + i) * 32 + (kc ^ jq)];
#pragma unroll
            for (int i = 0; i < 4; ++i)
                fv[i] = Fl[(4 * rq + i) * 32 + kc];
#pragma unroll
            for (int r = 0; r < 4; ++r) {
#pragma unroll
                for (int c = 0; c < 4; ++c) {
                    acc[r][c] += fv[r].x * wv[c].x + fv[r].y * wv[c].y
                               + fv[r].z * wv[c].z + fv[r].w * wv[c].w;
                }
            }
        }
        __syncthreads();

#pragma unroll
        for (int r = 0; r < 4; ++r) {
            float s  = acc[r][0] + acc[r][1] + acc[r][2] + acc[r][3];
            float s2 = acc[r][0] * acc[r][0] + acc[r][1] * acc[r][1]
                     + acc[r][2] * acc[r][2] + acc[r][3] * acc[r][3];
#pragma unroll
            for (int m = 1; m <= 16; m <<= 1) {
                s  += __shfl_xor(s, m);
                s2 += __shfl_xor(s2, m);
            }
            float mu   = s * (1.f / 128.f);
            float var  = s2 * (1.f / 128.f) - mu * mu;
            float rstd = rsqrtf(var + EPS_LN);

            float v0 = fmaxf((acc[r][0] - mu) * rstd * g4.x + be4.x, 0.f);
            float v1 = fmaxf((acc[r][1] - mu) * rstd * g4.y + be4.y, 0.f);
            float v2 = fmaxf((acc[r][2] - mu) * rstd * g4.z + be4.z, 0.f);
            float v3 = fmaxf((acc[r][3] - mu) * rstd * g4.w + be4.w, 0.f);

            float nsq = v0 * v0 + v1 * v1 + v2 * v2 + v3 * v3;
#pragma unroll
            for (int m = 1; m <= 16; m <<= 1) nsq += __shfl_xor(nsq, m);
            float inv = 1.f / fmaxf(sqrtf(nsq), EPS_COS);

            int grow = row0 + 4 * rq + r;
            if (grow < N) {
                us4 st;
                st[0] = f2bf(v0 * inv); st[1] = f2bf(v1 * inv);
                st[2] = f2bf(v2 * inv); st[3] = f2bf(v3 * inv);
                *(us4*)&hnb[(size_t)grow * 128 + jq * 4] = st;
            }
        }
    }
}

// ---------------- CSR build: histogram -> scan -> scatter -------------------
__global__ void hist_kernel(const int* __restrict__ s0, const int* __restrict__ s1,
                            const int* __restrict__ s2, int* __restrict__ cnt, int E)
{
    int i = blockIdx.x * blockDim.x + threadIdx.x;
    int stride = gridDim.x * blockDim.x;
    int tot = 3 * E;
    for (; i < tot; i += stride) {
        int src = (i < E) ? s0[i] : (i < 2 * E) ? s1[i - E] : s2[i - 2 * E];
        atomicAdd(&cnt[src], 1);
    }
}

// block scans 2048 elements (256 thr x 8)
__global__ void scan1_kernel(const int* __restrict__ cnt, int* __restrict__ part,
                             int* __restrict__ bsum, int N)
{
    __shared__ int sh[256];
    const int tid = threadIdx.x;
    const int base = blockIdx.x * 2048 + tid * 8;
    int v[8];
#pragma unroll
    for (int k = 0; k < 8; ++k) v[k] = (base + k < N) ? cnt[base + k] : 0;
    int tsum = 0;
#pragma unroll
    for (int k = 0; k < 8; ++k) { int t = v[k]; v[k] = tsum; tsum += t; }
    sh[tid] = tsum;
    __syncthreads();
    for (int off = 1; off < 256; off <<= 1) {
        int t = (tid >= off) ? sh[tid - off] : 0;
        __syncthreads();
        sh[tid] += t;
        __syncthreads();
    }
    int texcl = sh[tid] - tsum;
#pragma unroll
    for (int k = 0; k < 8; ++k)
        if (base + k < N) part[base + k] = v[k] + texcl;
    if (tid == 255) bsum[blockIdx.x] = sh[255];
}

__global__ void scan2_kernel(int* __restrict__ bsum, int nblk)
{
    if (blockIdx.x == 0 && threadIdx.x == 0) {
        int run = 0;
        for (int i = 0; i < nblk; ++i) { int t = bsum[i]; bsum[i] = run; run += t; }
    }
}

__global__ void scan3_kernel(int* __restrict__ row_ptr, const int* __restrict__ bsum,
                             int N, int totE)
{
    int i = blockIdx.x * blockDim.x + threadIdx.x;
    int stride = gridDim.x * blockDim.x;
    for (; i < N; i += stride) row_ptr[i] += bsum[i >> 11];
    if (blockIdx.x == 0 && threadIdx.x == 0) row_ptr[N] = totE;
}

// scatter edges into CSR slots; pack class into bits[24:26) of src word
__global__ void build_kernel(
    const int* __restrict__ s0, const int* __restrict__ d0,
    const int* __restrict__ s1, const int* __restrict__ d1,
    const int* __restrict__ s2, const int* __restrict__ d2,
    int* __restrict__ cursor, int* __restrict__ sd_csr, int* __restrict__ dst_csr,
    int E)
{
    int i = blockIdx.x * blockDim.x + threadIdx.x;
    int stride = gridDim.x * blockDim.x;
    int tot = 3 * E;
    for (; i < tot; i += stride) {
        int src, dst, cls;
        if (i < E)          { src = s0[i];         dst = d0[i];         cls = 0; }
        else if (i < 2 * E) { src = s1[i - E];     dst = d1[i - E];     cls = 1; }
        else                { src = s2[i - 2 * E]; dst = d2[i - 2 * E]; cls = 2; }
        int pos = atomicAdd(&cursor[src], 1);
        sd_csr[pos]  = src | (cls << 24);
        dst_csr[pos] = dst;
    }
}

// ---------------- sim over CSR: w[e] = sigmoid(ew[cls]) * cos(src,dst) ------
// 16 lanes per edge, us8 (16B, 8 bf16) per lane. src rows are grouped
// (CSR order) -> L1/L2 hits; dst random but hnb (25.6MB) is L3-resident.
__global__ void sim_csr_kernel(const unsigned short* __restrict__ hnb,
    const int* __restrict__ sd_csr, const int* __restrict__ dst_csr,
    const float* __restrict__ ew0, const float* __restrict__ ew1,
    const float* __restrict__ ew2, float* __restrict__ w_csr, int totE)
{
    const int gtid = blockIdx.x * blockDim.x + threadIdx.x;
    const int lane = gtid & 15;
    const int grp  = gtid >> 4;
    const int ngrp = (gridDim.x * blockDim.x) >> 4;
    const float sg0 = 1.f / (1.f + expf(-ew0[0]));
    const float sg1 = 1.f / (1.f + expf(-ew1[0]));
    const float sg2 = 1.f / (1.f + expf(-ew2[0]));
    for (int e = grp; e < totE; e += ngrp) {
        int sv  = sd_csr[e];
        int src = sv & 0xFFFFFF, cls = sv >> 24;
        int dst = dst_csr[e];
        us8 a = *(const us8*)&hnb[(size_t)src * 128 + lane * 8];
        us8 c = *(const us8*)&hnb[(size_t)dst * 128 + lane * 8];
        float p = 0.f;
#pragma unroll
        for (int k = 0; k < 8; ++k) p += bf2f(a[k]) * bf2f(c[k]);
#pragma unroll
        for (int m = 1; m <= 8; m <<= 1) p += __shfl_xor(p, m);
        if (lane == 0) {
            float sg = (cls == 0) ? sg0 : (cls == 1) ? sg1 : sg2;
            w_csr[e] = sg * p;
        }
    }
}

// ---------------- per-node scale from w segments -----------------------------
// 16 lanes per node, strided over its CSR segment.
__global__ void seg_scale_kernel(const int* __restrict__ row_ptr,
    const float* __restrict__ w_csr, float* __restrict__ scl, int N)
{
    const int gtid = blockIdx.x * blockDim.x + threadIdx.x;
    const int lane = gtid & 15;
    const int grp  = gtid >> 4;
    const int ngrp = (gridDim.x * blockDim.x) >> 4;
    for (int n = grp; n < N; n += ngrp) {
        int beg = row_ptr[n], end = row_ptr[n + 1];
        float t = 0.f;
        for (int e = beg + lane; e < end; e += 16) t += w_csr[e];
#pragma unroll
        for (int m = 1; m <= 8; m <<= 1) t += __shfl_xor(t, m);
        if (lane == 0) scl[n] = (t > 0.f) ? 1.f / t : 1.f;
    }
}

// ---------------- propagation layer: gather + finalize fused ----------------
// 16 lanes per node (one per class): out = a*scl*sum(w*cur[dst]) + (1-a)*init
__global__ void prop_kernel(const int* __restrict__ row_ptr,
    const int* __restrict__ dst_csr, const float* __restrict__ w_csr,
    const float* __restrict__ cur, const float* __restrict__ scl,
    const float* __restrict__ init, float* __restrict__ out, int N)
{
    const int gtid = blockIdx.x * blockDim.x + threadIdx.x;
    const int c    = gtid & 15;
    const int grp  = gtid >> 4;
    const int ngrp = (gridDim.x * blockDim.x) >> 4;
    for (int n = grp; n < N; n += ngrp) {
        int beg = row_ptr[n], end = row_ptr[n + 1];
        float acc = 0.f;
        for (int e = beg; e < end; ++e) {
            float w = w_csr[e];
            int  d  = dst_csr[e];
            acc += w * cur[(size_t)d * 16 + c];
        }
        out[(size_t)n * 16 + c] = ALPHA_ * scl[n] * acc
                                + (1.f - ALPHA_) * init[(size_t)n * 16 + c];
    }
}

extern "C" void kernel_launch(void* const* d_in, const int* in_sizes, int n_in,
                              void* d_out, int out_size, void* d_ws, size_t ws_size,
                              hipStream_t stream)
{
    const float* feat  = (const float*)d_in[0];
    const float* initl = (const float*)d_in[1];
    const float* W     = (const float*)d_in[2];
    const float* b     = (const float*)d_in[3];
    const float* gam   = (const float*)d_in[4];
    const float* bet   = (const float*)d_in[5];
    const float* ew0   = (const float*)d_in[6];
    const float* ew1   = (const float*)d_in[7];
    const float* ew2   = (const float*)d_in[8];
    const int* s0  = (const int*)d_in[9];
    const int* dd0 = (const int*)d_in[10];
    const int* s1  = (const int*)d_in[11];
    const int* dd1 = (const int*)d_in[12];
    const int* s2  = (const int*)d_in[13];
    const int* dd2 = (const int*)d_in[14];

    const int N = in_sizes[0] / DD;
    const int E = in_sizes[9];
    const int totE = 3 * E;
    float* out = (float*)d_out;

    char* ws = (char*)d_ws;
    size_t off = 0;
    auto alloc = [&](size_t bytes) -> void* {
        void* p = ws + off;
        off += (bytes + 255) & ~(size_t)255;
        return p;
    };
    unsigned short* hnb = (unsigned short*)alloc((size_t)N * DD * 2);
    int*   cnt     = (int*)alloc((size_t)N * 4);
    int*   row_ptr = (int*)alloc((size_t)(N + 1) * 4);
    int*   cursor  = (int*)alloc((size_t)N * 4);
    int*   bsum    = (int*)alloc(4096);
    int*   sd_csr  = (int*)alloc((size_t)totE * 4);
    int*   dst_csr = (int*)alloc((size_t)totE * 4);
    float* w_csr   = (float*)alloc((size_t)totE * 4);
    float* scl     = (float*)alloc((size_t)N * 4);
    float* cur     = (float*)alloc((size_t)N * CC * 4);

    // 1) feature transform -> bf16 normalized rows
    ft_kernel<<<512, 256, 0, stream>>>(feat, W, b, gam, bet, hnb, N);

    // 2) CSR build (counting sort by src)
    hipMemsetAsync(cnt, 0, (size_t)N * 4, stream);
    hist_kernel<<<1024, 256, 0, stream>>>(s0, s1, s2, cnt, E);
    const int nblk = (N + 2047) / 2048;
    scan1_kernel<<<nblk, 256, 0, stream>>>(cnt, row_ptr, bsum, N);
    scan2_kernel<<<1, 64, 0, stream>>>(bsum, nblk);
    scan3_kernel<<<256, 256, 0, stream>>>(row_ptr, bsum, N, totE);
    hipMemcpyAsync(cursor, row_ptr, (size_t)N * 4, hipMemcpyDeviceToDevice, stream);
    build_kernel<<<1024, 256, 0, stream>>>(s0, dd0, s1, dd1, s2, dd2,
                                           cursor, sd_csr, dst_csr, E);

    // 3) edge weights + per-node scale
    sim_csr_kernel<<<2048, 256, 0, stream>>>(hnb, sd_csr, dst_csr,
                                             ew0, ew1, ew2, w_csr, totE);
    seg_scale_kernel<<<512, 256, 0, stream>>>(row_ptr, w_csr, scl, N);

    // 4) 5 propagation layers (gather, fused finalize)
    const float* cs = initl;
    for (int layer = 0; layer < 5; ++layer) {
        float* dst = (layer == 4) ? out : cur;
        prop_kernel<<<2048, 256, 0, stream>>>(row_ptr, dst_csr, w_csr,
                                              cs, scl, initl, dst, N);
        cs = cur;
    }
}

// Round 4
// 1072.152 us; speedup vs baseline: 3.8630x; 1.0165x over previous
//
#include <hip/hip_runtime.h>
#include <math.h>

#define DD 128
#define CC 16
#define ALPHA_ 0.5f
#define EPS_LN 1e-5f
#define EPS_COS 1e-8f

typedef __attribute__((ext_vector_type(8))) unsigned short us8;
typedef __attribute__((ext_vector_type(4))) unsigned short us4;

__device__ __forceinline__ unsigned short f2bf(float x) {
    unsigned u = __float_as_uint(x);
    u += 0x7FFFu + ((u >> 16) & 1u);   // RNE
    return (unsigned short)(u >> 16);
}
__device__ __forceinline__ float bf2f(unsigned short v) {
    return __uint_as_float((unsigned)v << 16);
}

// ---------------- Kernel A: feature transform -> bf16 L2-normalized rows ----
__global__ __launch_bounds__(256, 2) void ft_kernel(
    const float* __restrict__ feat, const float* __restrict__ W,
    const float* __restrict__ b, const float* __restrict__ gamma,
    const float* __restrict__ beta, unsigned short* __restrict__ hnb, int N)
{
    __shared__ float4 Wl[128 * 32];   // 64 KB
    __shared__ float4 Fl[32 * 32];    // 16 KB

    const int tid = threadIdx.x;
    const int jq  = tid & 31;
    const int rq  = tid >> 5;

    const float4* Wg = (const float4*)W;
    for (int idx = tid; idx < 128 * 32; idx += 256) {
        int r = idx >> 5, kc = idx & 31;
        Wl[r * 32 + (kc ^ ((r >> 2) & 31))] = Wg[idx];
    }
    const float4 b4  = ((const float4*)b)[jq];
    const float4 g4  = ((const float4*)gamma)[jq];
    const float4 be4 = ((const float4*)beta)[jq];
    __syncthreads();

    const int iters = (N + 31) >> 5;
    for (int g = blockIdx.x; g < iters; g += gridDim.x) {
        const int row0 = g << 5;
        for (int t = 0; t < 4; ++t) {
            int idx = tid + t * 256;
            int r = idx >> 5;
            int grow = row0 + r;
            Fl[idx] = (grow < N) ? ((const float4*)feat)[(size_t)grow * 32 + (idx & 31)]
                                 : make_float4(0.f, 0.f, 0.f, 0.f);
        }
        __syncthreads();

        float acc[4][4];
#pragma unroll
        for (int r = 0; r < 4; ++r) {
            acc[r][0] = b4.x; acc[r][1] = b4.y; acc[r][2] = b4.z; acc[r][3] = b4.w;
        }
#pragma unroll 2
        for (int kc = 0; kc < 32; ++kc) {
            float4 wv[4], fv[4];
#pragma unroll
            for (int i = 0; i < 4; ++i)
                wv[i] = Wl[(4 * jq + i) * 32 + (kc ^ jq)];
#pragma unroll
            for (int i = 0; i < 4; ++i)
                fv[i] = Fl[(4 * rq + i) * 32 + kc];
#pragma unroll
            for (int r = 0; r < 4; ++r) {
#pragma unroll
                for (int c = 0; c < 4; ++c) {
                    acc[r][c] += fv[r].x * wv[c].x + fv[r].y * wv[c].y
                               + fv[r].z * wv[c].z + fv[r].w * wv[c].w;
                }
            }
        }
        __syncthreads();

#pragma unroll
        for (int r = 0; r < 4; ++r) {
            float s  = acc[r][0] + acc[r][1] + acc[r][2] + acc[r][3];
            float s2 = acc[r][0] * acc[r][0] + acc[r][1] * acc[r][1]
                     + acc[r][2] * acc[r][2] + acc[r][3] * acc[r][3];
#pragma unroll
            for (int m = 1; m <= 16; m <<= 1) {
                s  += __shfl_xor(s, m);
                s2 += __shfl_xor(s2, m);
            }
            float mu   = s * (1.f / 128.f);
            float var  = s2 * (1.f / 128.f) - mu * mu;
            float rstd = rsqrtf(var + EPS_LN);

            float v0 = fmaxf((acc[r][0] - mu) * rstd * g4.x + be4.x, 0.f);
            float v1 = fmaxf((acc[r][1] - mu) * rstd * g4.y + be4.y, 0.f);
            float v2 = fmaxf((acc[r][2] - mu) * rstd * g4.z + be4.z, 0.f);
            float v3 = fmaxf((acc[r][3] - mu) * rstd * g4.w + be4.w, 0.f);

            float nsq = v0 * v0 + v1 * v1 + v2 * v2 + v3 * v3;
#pragma unroll
            for (int m = 1; m <= 16; m <<= 1) nsq += __shfl_xor(nsq, m);
            float inv = 1.f / fmaxf(sqrtf(nsq), EPS_COS);

            int grow = row0 + 4 * rq + r;
            if (grow < N) {
                us4 st;
                st[0] = f2bf(v0 * inv); st[1] = f2bf(v1 * inv);
                st[2] = f2bf(v2 * inv); st[3] = f2bf(v3 * inv);
                *(us4*)&hnb[(size_t)grow * 128 + jq * 4] = st;
            }
        }
    }
}

// ---------------- CSR build: histogram -> scan -> scatter -------------------
__global__ void hist_kernel(const int* __restrict__ s0, const int* __restrict__ s1,
                            const int* __restrict__ s2, int* __restrict__ cnt, int E)
{
    int i = blockIdx.x * blockDim.x + threadIdx.x;
    int tot = 3 * E;
    if (i < tot) {
        int src = (i < E) ? s0[i] : (i < 2 * E) ? s1[i - E] : s2[i - 2 * E];
        atomicAdd(&cnt[src], 1);
    }
}

// block scans 2048 elements (256 thr x 8)
__global__ void scan1_kernel(const int* __restrict__ cnt, int* __restrict__ part,
                             int* __restrict__ bsum, int N)
{
    __shared__ int sh[256];
    const int tid = threadIdx.x;
    const int base = blockIdx.x * 2048 + tid * 8;
    int v[8];
#pragma unroll
    for (int k = 0; k < 8; ++k) v[k] = (base + k < N) ? cnt[base + k] : 0;
    int tsum = 0;
#pragma unroll
    for (int k = 0; k < 8; ++k) { int t = v[k]; v[k] = tsum; tsum += t; }
    sh[tid] = tsum;
    __syncthreads();
    for (int off = 1; off < 256; off <<= 1) {
        int t = (tid >= off) ? sh[tid - off] : 0;
        __syncthreads();
        sh[tid] += t;
        __syncthreads();
    }
    int texcl = sh[tid] - tsum;
#pragma unroll
    for (int k = 0; k < 8; ++k)
        if (base + k < N) part[base + k] = v[k] + texcl;
    if (tid == 255) bsum[blockIdx.x] = sh[255];
}

__global__ void scan2_kernel(int* __restrict__ bsum, int nblk)
{
    if (blockIdx.x == 0 && threadIdx.x == 0) {
        int run = 0;
        for (int i = 0; i < nblk; ++i) { int t = bsum[i]; bsum[i] = run; run += t; }
    }
}

// adds block offsets; also emits the cursor copy (saves a d2d memcpy)
__global__ void scan3_kernel(int* __restrict__ row_ptr, int* __restrict__ cursor,
                             const int* __restrict__ bsum, int N, int totE)
{
    int i = blockIdx.x * blockDim.x + threadIdx.x;
    int stride = gridDim.x * blockDim.x;
    for (; i < N; i += stride) {
        int v = row_ptr[i] + bsum[i >> 11];
        row_ptr[i] = v;
        cursor[i]  = v;
    }
    if (blockIdx.x == 0 && threadIdx.x == 0) row_ptr[N] = totE;
}

// scatter edges into CSR: single 4B payload dst | cls<<24
__global__ void build_kernel(
    const int* __restrict__ s0, const int* __restrict__ d0,
    const int* __restrict__ s1, const int* __restrict__ d1,
    const int* __restrict__ s2, const int* __restrict__ d2,
    int* __restrict__ cursor, int* __restrict__ dstc_csr, int E)
{
    int i = blockIdx.x * blockDim.x + threadIdx.x;
    int tot = 3 * E;
    if (i < tot) {
        int src, dst, cls;
        if (i < E)          { src = s0[i];         dst = d0[i];         cls = 0; }
        else if (i < 2 * E) { src = s1[i - E];     dst = d1[i - E];     cls = 1; }
        else                { src = s2[i - 2 * E]; dst = d2[i - 2 * E]; cls = 2; }
        int pos = atomicAdd(&cursor[src], 1);
        dstc_csr[pos] = dst | (cls << 24);
    }
}

// ---------------- fused per-node sim + total + alpha/scl fold ---------------
// 16 lanes per node. src row held in registers (us8/lane = 128 bf16).
// Butterfly reduce leaves the dot in ALL lanes, so every lane tracks total
// locally. Owner lane (k&15)==lane stores raw w; after the loop it rescales
// its OWN stores by s = ALPHA * (total>0 ? 1/total : 1)  (same-thread
// load-after-store => visibility guaranteed).
__global__ void node_sim_kernel(const unsigned short* __restrict__ hnb,
    const int* __restrict__ row_ptr, const int* __restrict__ dstc_csr,
    const float* __restrict__ ew0, const float* __restrict__ ew1,
    const float* __restrict__ ew2, float* __restrict__ w_csr, int N)
{
    const int gtid = blockIdx.x * blockDim.x + threadIdx.x;
    const int lane = gtid & 15;
    const int grp  = gtid >> 4;
    const int ngrp = (gridDim.x * blockDim.x) >> 4;
    const float sg0 = 1.f / (1.f + expf(-ew0[0]));
    const float sg1 = 1.f / (1.f + expf(-ew1[0]));
    const float sg2 = 1.f / (1.f + expf(-ew2[0]));
    for (int n = grp; n < N; n += ngrp) {
        const int beg = row_ptr[n], end = row_ptr[n + 1];
        if (beg == end) continue;
        us8 a = *(const us8*)&hnb[(size_t)n * 128 + lane * 8];
        float af[8];
#pragma unroll
        for (int k = 0; k < 8; ++k) af[k] = bf2f(a[k]);

        float total = 0.f;
        int k = 0;
        for (int e = beg; e < end; ++e, ++k) {
            int v = dstc_csr[e];
            int dst = v & 0xFFFFFF;
            us8 c = *(const us8*)&hnb[(size_t)dst * 128 + lane * 8];
            float p = 0.f;
#pragma unroll
            for (int q = 0; q < 8; ++q) p += af[q] * bf2f(c[q]);
#pragma unroll
            for (int m = 1; m <= 8; m <<= 1) p += __shfl_xor(p, m);
            int cls = v >> 24;
            float w = ((cls == 0) ? sg0 : (cls == 1) ? sg1 : sg2) * p;
            total += w;
            if ((k & 15) == lane) w_csr[e] = w;
        }
        float s = ALPHA_ * ((total > 0.f) ? 1.f / total : 1.f);
        for (int e = beg + lane; e < end; e += 16)
            w_csr[e] *= s;   // re-reads this thread's own stores
    }
}

// ---------------- propagation layer: out = sum(w'*cur[dst]) + 0.5*init -----
__global__ void prop_kernel(const int* __restrict__ row_ptr,
    const int* __restrict__ dstc_csr, const float* __restrict__ w_csr,
    const float* __restrict__ cur, const float* __restrict__ init,
    float* __restrict__ out, int N)
{
    const int gtid = blockIdx.x * blockDim.x + threadIdx.x;
    const int c    = gtid & 15;
    const int grp  = gtid >> 4;
    const int ngrp = (gridDim.x * blockDim.x) >> 4;
    for (int n = grp; n < N; n += ngrp) {
        int beg = row_ptr[n], end = row_ptr[n + 1];
        float acc = 0.f;
        for (int e = beg; e < end; ++e) {
            float w = w_csr[e];
            int  d  = dstc_csr[e] & 0xFFFFFF;
            acc += w * cur[(size_t)d * 16 + c];
        }
        out[(size_t)n * 16 + c] = acc + (1.f - ALPHA_) * init[(size_t)n * 16 + c];
    }
}

extern "C" void kernel_launch(void* const* d_in, const int* in_sizes, int n_in,
                              void* d_out, int out_size, void* d_ws, size_t ws_size,
                              hipStream_t stream)
{
    const float* feat  = (const float*)d_in[0];
    const float* initl = (const float*)d_in[1];
    const float* W     = (const float*)d_in[2];
    const float* b     = (const float*)d_in[3];
    const float* gam   = (const float*)d_in[4];
    const float* bet   = (const float*)d_in[5];
    const float* ew0   = (const float*)d_in[6];
    const float* ew1   = (const float*)d_in[7];
    const float* ew2   = (const float*)d_in[8];
    const int* s0  = (const int*)d_in[9];
    const int* dd0 = (const int*)d_in[10];
    const int* s1  = (const int*)d_in[11];
    const int* dd1 = (const int*)d_in[12];
    const int* s2  = (const int*)d_in[13];
    const int* dd2 = (const int*)d_in[14];

    const int N = in_sizes[0] / DD;
    const int E = in_sizes[9];
    const int totE = 3 * E;
    float* out = (float*)d_out;

    char* ws = (char*)d_ws;
    size_t off = 0;
    auto alloc = [&](size_t bytes) -> void* {
        void* p = ws + off;
        off += (bytes + 255) & ~(size_t)255;
        return p;
    };
    unsigned short* hnb = (unsigned short*)alloc((size_t)N * DD * 2);
    int*   cnt      = (int*)alloc((size_t)N * 4);
    int*   row_ptr  = (int*)alloc((size_t)(N + 1) * 4);
    int*   cursor   = (int*)alloc((size_t)N * 4);
    int*   bsum     = (int*)alloc(4096);
    int*   dstc_csr = (int*)alloc((size_t)totE * 4);
    float* w_csr    = (float*)alloc((size_t)totE * 4);
    float* cur      = (float*)alloc((size_t)N * CC * 4);

    // 1) feature transform -> bf16 normalized rows
    ft_kernel<<<512, 256, 0, stream>>>(feat, W, b, gam, bet, hnb, N);

    // 2) CSR build (counting sort by src), 1 edge per thread
    const int eblk = (totE + 255) / 256;
    hipMemsetAsync(cnt, 0, (size_t)N * 4, stream);
    hist_kernel<<<eblk, 256, 0, stream>>>(s0, s1, s2, cnt, E);
    const int nblk = (N + 2047) / 2048;
    scan1_kernel<<<nblk, 256, 0, stream>>>(cnt, row_ptr, bsum, N);
    scan2_kernel<<<1, 64, 0, stream>>>(bsum, nblk);
    scan3_kernel<<<256, 256, 0, stream>>>(row_ptr, cursor, bsum, N, totE);
    build_kernel<<<eblk, 256, 0, stream>>>(s0, dd0, s1, dd1, s2, dd2,
                                           cursor, dstc_csr, E);

    // 3) fused edge weights + per-node normalize (alpha/scl folded in)
    const int gblk = (N * 16 + 255) / 256;
    node_sim_kernel<<<gblk, 256, 0, stream>>>(hnb, row_ptr, dstc_csr,
                                              ew0, ew1, ew2, w_csr, N);

    // 4) 5 propagation layers (gather, fused finalize)
    const float* cs = initl;
    for (int layer = 0; layer < 5; ++layer) {
        float* dst = (layer == 4) ? out : cur;
        prop_kernel<<<gblk, 256, 0, stream>>>(row_ptr, dstc_csr, w_csr,
                                              cs, initl, dst, N);
        cs = cur;
    }
}

// Round 5
// 806.237 us; speedup vs baseline: 5.1372x; 1.3298x over previous
//
#include <hip/hip_runtime.h>
#include <math.h>

#define DD 128
#define CC 16
#define ALPHA_ 0.5f
#define EPS_LN 1e-5f
#define EPS_COS 1e-8f

typedef __attribute__((ext_vector_type(8))) unsigned short us8;
typedef __attribute__((ext_vector_type(4))) unsigned short us4;

__device__ __forceinline__ unsigned short f2bf(float x) {
    unsigned u = __float_as_uint(x);
    u += 0x7FFFu + ((u >> 16) & 1u);   // RNE
    return (unsigned short)(u >> 16);
}
__device__ __forceinline__ float bf2f(unsigned short v) {
    return __uint_as_float((unsigned)v << 16);
}

// ---------------- Kernel A: feature transform -> bf16 L2-normalized rows ----
__global__ __launch_bounds__(256, 2) void ft_kernel(
    const float* __restrict__ feat, const float* __restrict__ W,
    const float* __restrict__ b, const float* __restrict__ gamma,
    const float* __restrict__ beta, unsigned short* __restrict__ hnb, int N)
{
    __shared__ float4 Wl[128 * 32];   // 64 KB
    __shared__ float4 Fl[32 * 32];    // 16 KB

    const int tid = threadIdx.x;
    const int jq  = tid & 31;
    const int rq  = tid >> 5;

    const float4* Wg = (const float4*)W;
    for (int idx = tid; idx < 128 * 32; idx += 256) {
        int r = idx >> 5, kc = idx & 31;
        Wl[r * 32 + (kc ^ ((r >> 2) & 31))] = Wg[idx];
    }
    const float4 b4  = ((const float4*)b)[jq];
    const float4 g4  = ((const float4*)gamma)[jq];
    const float4 be4 = ((const float4*)beta)[jq];
    __syncthreads();

    const int iters = (N + 31) >> 5;
    for (int g = blockIdx.x; g < iters; g += gridDim.x) {
        const int row0 = g << 5;
        for (int t = 0; t < 4; ++t) {
            int idx = tid + t * 256;
            int r = idx >> 5;
            int grow = row0 + r;
            Fl[idx] = (grow < N) ? ((const float4*)feat)[(size_t)grow * 32 + (idx & 31)]
                                 : make_float4(0.f, 0.f, 0.f, 0.f);
        }
        __syncthreads();

        float acc[4][4];
#pragma unroll
        for (int r = 0; r < 4; ++r) {
            acc[r][0] = b4.x; acc[r][1] = b4.y; acc[r][2] = b4.z; acc[r][3] = b4.w;
        }
#pragma unroll 2
        for (int kc = 0; kc < 32; ++kc) {
            float4 wv[4], fv[4];
#pragma unroll
            for (int i = 0; i < 4; ++i)
                wv[i] = Wl[(4 * jq + i) * 32 + (kc ^ jq)];
#pragma unroll
            for (int i = 0; i < 4; ++i)
                fv[i] = Fl[(4 * rq + i) * 32 + kc];
#pragma unroll
            for (int r = 0; r < 4; ++r) {
#pragma unroll
                for (int c = 0; c < 4; ++c) {
                    acc[r][c] += fv[r].x * wv[c].x + fv[r].y * wv[c].y
                               + fv[r].z * wv[c].z + fv[r].w * wv[c].w;
                }
            }
        }
        __syncthreads();

#pragma unroll
        for (int r = 0; r < 4; ++r) {
            float s  = acc[r][0] + acc[r][1] + acc[r][2] + acc[r][3];
            float s2 = acc[r][0] * acc[r][0] + acc[r][1] * acc[r][1]
                     + acc[r][2] * acc[r][2] + acc[r][3] * acc[r][3];
#pragma unroll
            for (int m = 1; m <= 16; m <<= 1) {
                s  += __shfl_xor(s, m);
                s2 += __shfl_xor(s2, m);
            }
            float mu   = s * (1.f / 128.f);
            float var  = s2 * (1.f / 128.f) - mu * mu;
            float rstd = rsqrtf(var + EPS_LN);

            float v0 = fmaxf((acc[r][0] - mu) * rstd * g4.x + be4.x, 0.f);
            float v1 = fmaxf((acc[r][1] - mu) * rstd * g4.y + be4.y, 0.f);
            float v2 = fmaxf((acc[r][2] - mu) * rstd * g4.z + be4.z, 0.f);
            float v3 = fmaxf((acc[r][3] - mu) * rstd * g4.w + be4.w, 0.f);

            float nsq = v0 * v0 + v1 * v1 + v2 * v2 + v3 * v3;
#pragma unroll
            for (int m = 1; m <= 16; m <<= 1) nsq += __shfl_xor(nsq, m);
            float inv = 1.f / fmaxf(sqrtf(nsq), EPS_COS);

            int grow = row0 + 4 * rq + r;
            if (grow < N) {
                us4 st;
                st[0] = f2bf(v0 * inv); st[1] = f2bf(v1 * inv);
                st[2] = f2bf(v2 * inv); st[3] = f2bf(v3 * inv);
                *(us4*)&hnb[(size_t)grow * 128 + jq * 4] = st;
            }
        }
    }
}

// ---------------- CSR build, XCD-partitioned --------------------------------
// blockIdx&7 = swizzle class (round-robin XCD). Class r scans ALL edges but
// only handles src in its node range -> all writes to a cursor/CSR line come
// from one XCD -> line stays in that XCD's L2 (no cross-XCD write thrash).
__global__ void hist_kernel(const int* __restrict__ s0, const int* __restrict__ s1,
                            const int* __restrict__ s2, int* __restrict__ cnt,
                            int E, int N)
{
    const int cls8 = blockIdx.x & 7;
    const int bidx = blockIdx.x >> 3;
    const int nb   = gridDim.x >> 3;
    const int rng  = (N + 7) >> 3;
    const int lo = cls8 * rng, hi = min(lo + rng, N);
    const int tot = 3 * E;
    for (int i = bidx * blockDim.x + threadIdx.x; i < tot; i += nb * blockDim.x) {
        int src = (i < E) ? s0[i] : (i < 2 * E) ? s1[i - E] : s2[i - 2 * E];
        if (src >= lo && src < hi) atomicAdd(&cnt[src], 1);
    }
}

// block scans 2048 elements (256 thr x 8)
__global__ void scan1_kernel(const int* __restrict__ cnt, int* __restrict__ part,
                             int* __restrict__ bsum, int N)
{
    __shared__ int sh[256];
    const int tid = threadIdx.x;
    const int base = blockIdx.x * 2048 + tid * 8;
    int v[8];
#pragma unroll
    for (int k = 0; k < 8; ++k) v[k] = (base + k < N) ? cnt[base + k] : 0;
    int tsum = 0;
#pragma unroll
    for (int k = 0; k < 8; ++k) { int t = v[k]; v[k] = tsum; tsum += t; }
    sh[tid] = tsum;
    __syncthreads();
    for (int off = 1; off < 256; off <<= 1) {
        int t = (tid >= off) ? sh[tid - off] : 0;
        __syncthreads();
        sh[tid] += t;
        __syncthreads();
    }
    int texcl = sh[tid] - tsum;
#pragma unroll
    for (int k = 0; k < 8; ++k)
        if (base + k < N) part[base + k] = v[k] + texcl;
    if (tid == 255) bsum[blockIdx.x] = sh[255];
}

__global__ void scan2_kernel(int* __restrict__ bsum, int nblk)
{
    if (blockIdx.x == 0 && threadIdx.x == 0) {
        int run = 0;
        for (int i = 0; i < nblk; ++i) { int t = bsum[i]; bsum[i] = run; run += t; }
    }
}

__global__ void scan3_kernel(int* __restrict__ row_ptr, int* __restrict__ cursor,
                             const int* __restrict__ bsum, int N, int totE)
{
    int i = blockIdx.x * blockDim.x + threadIdx.x;
    int stride = gridDim.x * blockDim.x;
    for (; i < N; i += stride) {
        int v = row_ptr[i] + bsum[i >> 11];
        row_ptr[i] = v;
        cursor[i]  = v;
    }
    if (blockIdx.x == 0 && threadIdx.x == 0) row_ptr[N] = totE;
}

__global__ void build_kernel(
    const int* __restrict__ s0, const int* __restrict__ d0,
    const int* __restrict__ s1, const int* __restrict__ d1,
    const int* __restrict__ s2, const int* __restrict__ d2,
    int* __restrict__ cursor, int* __restrict__ dstc_csr, int E, int N)
{
    const int cls8 = blockIdx.x & 7;
    const int bidx = blockIdx.x >> 3;
    const int nb   = gridDim.x >> 3;
    const int rng  = (N + 7) >> 3;
    const int lo = cls8 * rng, hi = min(lo + rng, N);
    const int tot = 3 * E;
    for (int i = bidx * blockDim.x + threadIdx.x; i < tot; i += nb * blockDim.x) {
        int src, dst, cls;
        if (i < E)          { src = s0[i];         dst = d0[i];         cls = 0; }
        else if (i < 2 * E) { src = s1[i - E];     dst = d1[i - E];     cls = 1; }
        else                { src = s2[i - 2 * E]; dst = d2[i - 2 * E]; cls = 2; }
        if (src < lo || src >= hi) continue;
        int pos = atomicAdd(&cursor[src], 1);
        dstc_csr[pos] = dst | (cls << 24);
    }
}

// ---------------- fused per-node sim + total + alpha/scl fold ---------------
// One 64-lane wave per node: 4 edge-subgroups (sg=lane>>4) x 16 lanes.
// Subgroup sg handles edges k = sg, sg+4, ... (4 dst-row gathers in flight).
// Dot reduce is within-16 (xor 1..8); total reduced across subgroups at end.
// Edge k's w stored (with dstc packed alongside) by lane (sg=k&3,l16=(k>>2)&15);
// the SAME lane later rescales k = 4*l16+sg+64j -> same-thread load-after-store.
__global__ void node_sim_kernel(const unsigned short* __restrict__ hnb,
    const int* __restrict__ row_ptr, const int* __restrict__ dstc_csr,
    const float* __restrict__ ew0, const float* __restrict__ ew1,
    const float* __restrict__ ew2, float2* __restrict__ wd_csr, int N)
{
    const int gtid = blockIdx.x * blockDim.x + threadIdx.x;
    const int lane = threadIdx.x & 63;
    const int sg   = lane >> 4;
    const int l16  = lane & 15;
    const int wv   = gtid >> 6;
    const int nwv  = (gridDim.x * blockDim.x) >> 6;
    const float sg0 = 1.f / (1.f + expf(-ew0[0]));
    const float sg1 = 1.f / (1.f + expf(-ew1[0]));
    const float sg2 = 1.f / (1.f + expf(-ew2[0]));
    for (int n = wv; n < N; n += nwv) {
        const int beg = row_ptr[n], end = row_ptr[n + 1];
        const int deg = end - beg;
        if (deg == 0) continue;
        us8 a = *(const us8*)&hnb[(size_t)n * 128 + l16 * 8];
        float af[8];
#pragma unroll
        for (int q = 0; q < 8; ++q) af[q] = bf2f(a[q]);

        float total = 0.f;
        for (int k = sg; k < deg; k += 4) {
            int e = beg + k;
            int v = dstc_csr[e];
            int dst = v & 0xFFFFFF;
            us8 c = *(const us8*)&hnb[(size_t)dst * 128 + l16 * 8];
            float p = 0.f;
#pragma unroll
            for (int q = 0; q < 8; ++q) p += af[q] * bf2f(c[q]);
#pragma unroll
            for (int m = 1; m <= 8; m <<= 1) p += __shfl_xor(p, m);
            int cls = v >> 24;
            float w = ((cls == 0) ? sg0 : (cls == 1) ? sg1 : sg2) * p;
            total += w;
            if (((k >> 2) & 15) == l16) {
                float2 wd; wd.x = w; wd.y = __int_as_float(v);
                wd_csr[e] = wd;
            }
        }
        // cross-subgroup total (within-subgroup lanes hold identical values)
        total += __shfl_xor(total, 16);
        total += __shfl_xor(total, 32);
        float s = ALPHA_ * ((total > 0.f) ? 1.f / total : 1.f);
        for (int k = 4 * l16 + sg; k < deg; k += 64)
            wd_csr[beg + k].x *= s;   // same-thread RMW of own store
    }
}

// ---------------- propagation: out = sum(w'*cur[dst]) + 0.5*init ------------
// One wave per node, 4 edge-subgroups, class c = lane&15.
__global__ void prop_kernel(const int* __restrict__ row_ptr,
    const float2* __restrict__ wd_csr,
    const float* __restrict__ cur, const float* __restrict__ init,
    float* __restrict__ out, int N)
{
    const int gtid = blockIdx.x * blockDim.x + threadIdx.x;
    const int lane = threadIdx.x & 63;
    const int sg   = lane >> 4;
    const int c    = lane & 15;
    const int wv   = gtid >> 6;
    const int nwv  = (gridDim.x * blockDim.x) >> 6;
    for (int n = wv; n < N; n += nwv) {
        int beg = row_ptr[n], end = row_ptr[n + 1];
        float acc = 0.f;
#pragma unroll 2
        for (int e = beg + sg; e < end; e += 4) {
            float2 wd = wd_csr[e];
            int d = __float_as_int(wd.y) & 0xFFFFFF;
            acc += wd.x * cur[(size_t)d * 16 + c];
        }
        acc += __shfl_xor(acc, 16);
        acc += __shfl_xor(acc, 32);
        if (sg == 0)
            out[(size_t)n * 16 + c] = acc + (1.f - ALPHA_) * init[(size_t)n * 16 + c];
    }
}

extern "C" void kernel_launch(void* const* d_in, const int* in_sizes, int n_in,
                              void* d_out, int out_size, void* d_ws, size_t ws_size,
                              hipStream_t stream)
{
    const float* feat  = (const float*)d_in[0];
    const float* initl = (const float*)d_in[1];
    const float* W     = (const float*)d_in[2];
    const float* b     = (const float*)d_in[3];
    const float* gam   = (const float*)d_in[4];
    const float* bet   = (const float*)d_in[5];
    const float* ew0   = (const float*)d_in[6];
    const float* ew1   = (const float*)d_in[7];
    const float* ew2   = (const float*)d_in[8];
    const int* s0  = (const int*)d_in[9];
    const int* dd0 = (const int*)d_in[10];
    const int* s1  = (const int*)d_in[11];
    const int* dd1 = (const int*)d_in[12];
    const int* s2  = (const int*)d_in[13];
    const int* dd2 = (const int*)d_in[14];

    const int N = in_sizes[0] / DD;
    const int E = in_sizes[9];
    const int totE = 3 * E;
    float* out = (float*)d_out;

    char* ws = (char*)d_ws;
    size_t off = 0;
    auto alloc = [&](size_t bytes) -> void* {
        void* p = ws + off;
        off += (bytes + 255) & ~(size_t)255;
        return p;
    };
    unsigned short* hnb = (unsigned short*)alloc((size_t)N * DD * 2);
    int*    cnt      = (int*)alloc((size_t)N * 4);
    int*    row_ptr  = (int*)alloc((size_t)(N + 1) * 4);
    int*    cursor   = (int*)alloc((size_t)N * 4);
    int*    bsum     = (int*)alloc(4096);
    int*    dstc_csr = (int*)alloc((size_t)totE * 4);
    float2* wd_csr   = (float2*)alloc((size_t)totE * 8);
    float*  cur      = (float*)alloc((size_t)N * CC * 4);

    // 1) feature transform -> bf16 normalized rows
    ft_kernel<<<512, 256, 0, stream>>>(feat, W, b, gam, bet, hnb, N);

    // 2) CSR build (counting sort by src), XCD-partitioned
    hipMemsetAsync(cnt, 0, (size_t)N * 4, stream);
    hist_kernel<<<8192, 256, 0, stream>>>(s0, s1, s2, cnt, E, N);
    const int nblk = (N + 2047) / 2048;
    scan1_kernel<<<nblk, 256, 0, stream>>>(cnt, row_ptr, bsum, N);
    scan2_kernel<<<1, 64, 0, stream>>>(bsum, nblk);
    scan3_kernel<<<256, 256, 0, stream>>>(row_ptr, cursor, bsum, N, totE);
    build_kernel<<<8192, 256, 0, stream>>>(s0, dd0, s1, dd1, s2, dd2,
                                           cursor, dstc_csr, E, N);

    // 3) fused edge weights + per-node normalize (alpha/scl folded in)
    const int wblk = (N * 64 + 255) / 256;
    node_sim_kernel<<<wblk, 256, 0, stream>>>(hnb, row_ptr, dstc_csr,
                                              ew0, ew1, ew2, wd_csr, N);

    // 4) 5 propagation layers (gather, fused finalize)
    const float* cs = initl;
    for (int layer = 0; layer < 5; ++layer) {
        float* dst = (layer == 4) ? out : cur;
        prop_kernel<<<wblk, 256, 0, stream>>>(row_ptr, wd_csr, cs, initl, dst, N);
        cs = cur;
    }
}

// Round 6
// 762.090 us; speedup vs baseline: 5.4348x; 1.0579x over previous
//
#include <hip/hip_runtime.h>
#include <math.h>

#define DD 128
#define CC 16
#define ALPHA_ 0.5f
#define EPS_LN 1e-5f
#define EPS_COS 1e-8f

typedef _Float16 h2 __attribute__((ext_vector_type(2)));
typedef _Float16 h4 __attribute__((ext_vector_type(4)));
typedef _Float16 h8 __attribute__((ext_vector_type(8)));

union H8 { h8 v; h2 p[4]; };

__device__ __forceinline__ float dot8(const H8& a, const H8& c, float acc) {
#if __has_builtin(__builtin_amdgcn_fdot2)
#pragma unroll
    for (int q = 0; q < 4; ++q)
        acc = __builtin_amdgcn_fdot2(a.p[q], c.p[q], acc, false);
#else
#pragma unroll
    for (int q = 0; q < 4; ++q)
        acc += (float)a.p[q][0] * (float)c.p[q][0]
             + (float)a.p[q][1] * (float)c.p[q][1];
#endif
    return acc;
}

// ---------------- Kernel A: feature transform -> f16 L2-normalized rows ----
__global__ __launch_bounds__(256, 2) void ft_kernel(
    const float* __restrict__ feat, const float* __restrict__ W,
    const float* __restrict__ b, const float* __restrict__ gamma,
    const float* __restrict__ beta, _Float16* __restrict__ hnf, int N)
{
    __shared__ float4 Wl[128 * 32];   // 64 KB
    __shared__ float4 Fl[32 * 32];    // 16 KB

    const int tid = threadIdx.x;
    const int jq  = tid & 31;
    const int rq  = tid >> 5;

    const float4* Wg = (const float4*)W;
    for (int idx = tid; idx < 128 * 32; idx += 256) {
        int r = idx >> 5, kc = idx & 31;
        Wl[r * 32 + (kc ^ ((r >> 2) & 31))] = Wg[idx];
    }
    const float4 b4  = ((const float4*)b)[jq];
    const float4 g4  = ((const float4*)gamma)[jq];
    const float4 be4 = ((const float4*)beta)[jq];
    __syncthreads();

    const int iters = (N + 31) >> 5;
    for (int g = blockIdx.x; g < iters; g += gridDim.x) {
        const int row0 = g << 5;
        for (int t = 0; t < 4; ++t) {
            int idx = tid + t * 256;
            int r = idx >> 5;
            int grow = row0 + r;
            Fl[idx] = (grow < N) ? ((const float4*)feat)[(size_t)grow * 32 + (idx & 31)]
                                 : make_float4(0.f, 0.f, 0.f, 0.f);
        }
        __syncthreads();

        float acc[4][4];
#pragma unroll
        for (int r = 0; r < 4; ++r) {
            acc[r][0] = b4.x; acc[r][1] = b4.y; acc[r][2] = b4.z; acc[r][3] = b4.w;
        }
#pragma unroll 2
        for (int kc = 0; kc < 32; ++kc) {
            float4 wv[4], fv[4];
#pragma unroll
            for (int i = 0; i < 4; ++i)
                wv[i] = Wl[(4 * jq + i) * 32 + (kc ^ jq)];
#pragma unroll
            for (int i = 0; i < 4; ++i)
                fv[i] = Fl[(4 * rq + i) * 32 + kc];
#pragma unroll
            for (int r = 0; r < 4; ++r) {
#pragma unroll
                for (int c = 0; c < 4; ++c) {
                    acc[r][c] += fv[r].x * wv[c].x + fv[r].y * wv[c].y
                               + fv[r].z * wv[c].z + fv[r].w * wv[c].w;
                }
            }
        }
        __syncthreads();

#pragma unroll
        for (int r = 0; r < 4; ++r) {
            float s  = acc[r][0] + acc[r][1] + acc[r][2] + acc[r][3];
            float s2 = acc[r][0] * acc[r][0] + acc[r][1] * acc[r][1]
                     + acc[r][2] * acc[r][2] + acc[r][3] * acc[r][3];
#pragma unroll
            for (int m = 1; m <= 16; m <<= 1) {
                s  += __shfl_xor(s, m);
                s2 += __shfl_xor(s2, m);
            }
            float mu   = s * (1.f / 128.f);
            float var  = s2 * (1.f / 128.f) - mu * mu;
            float rstd = rsqrtf(var + EPS_LN);

            float v0 = fmaxf((acc[r][0] - mu) * rstd * g4.x + be4.x, 0.f);
            float v1 = fmaxf((acc[r][1] - mu) * rstd * g4.y + be4.y, 0.f);
            float v2 = fmaxf((acc[r][2] - mu) * rstd * g4.z + be4.z, 0.f);
            float v3 = fmaxf((acc[r][3] - mu) * rstd * g4.w + be4.w, 0.f);

            float nsq = v0 * v0 + v1 * v1 + v2 * v2 + v3 * v3;
#pragma unroll
            for (int m = 1; m <= 16; m <<= 1) nsq += __shfl_xor(nsq, m);
            float inv = 1.f / fmaxf(sqrtf(nsq), EPS_COS);

            int grow = row0 + 4 * rq + r;
            if (grow < N) {
                h4 st;
                st[0] = (_Float16)(v0 * inv); st[1] = (_Float16)(v1 * inv);
                st[2] = (_Float16)(v2 * inv); st[3] = (_Float16)(v3 * inv);
                *(h4*)&hnf[(size_t)grow * 128 + jq * 4] = st;
            }
        }
    }
}

// ---------------- CSR build, XCD-partitioned --------------------------------
__global__ void hist_kernel(const int* __restrict__ s0, const int* __restrict__ s1,
                            const int* __restrict__ s2, int* __restrict__ cnt,
                            int E, int N)
{
    const int cls8 = blockIdx.x & 7;
    const int bidx = blockIdx.x >> 3;
    const int nb   = gridDim.x >> 3;
    const int rng  = (N + 7) >> 3;
    const int lo = cls8 * rng, hi = min(lo + rng, N);
    const int tot = 3 * E;
    for (int i = bidx * blockDim.x + threadIdx.x; i < tot; i += nb * blockDim.x) {
        int src = (i < E) ? s0[i] : (i < 2 * E) ? s1[i - E] : s2[i - 2 * E];
        if (src >= lo && src < hi) atomicAdd(&cnt[src], 1);
    }
}

__global__ void scan1_kernel(const int* __restrict__ cnt, int* __restrict__ part,
                             int* __restrict__ bsum, int N)
{
    __shared__ int sh[256];
    const int tid = threadIdx.x;
    const int base = blockIdx.x * 2048 + tid * 8;
    int v[8];
#pragma unroll
    for (int k = 0; k < 8; ++k) v[k] = (base + k < N) ? cnt[base + k] : 0;
    int tsum = 0;
#pragma unroll
    for (int k = 0; k < 8; ++k) { int t = v[k]; v[k] = tsum; tsum += t; }
    sh[tid] = tsum;
    __syncthreads();
    for (int off = 1; off < 256; off <<= 1) {
        int t = (tid >= off) ? sh[tid - off] : 0;
        __syncthreads();
        sh[tid] += t;
        __syncthreads();
    }
    int texcl = sh[tid] - tsum;
#pragma unroll
    for (int k = 0; k < 8; ++k)
        if (base + k < N) part[base + k] = v[k] + texcl;
    if (tid == 255) bsum[blockIdx.x] = sh[255];
}

__global__ void scan2_kernel(int* __restrict__ bsum, int nblk)
{
    if (blockIdx.x == 0 && threadIdx.x == 0) {
        int run = 0;
        for (int i = 0; i < nblk; ++i) { int t = bsum[i]; bsum[i] = run; run += t; }
    }
}

__global__ void scan3_kernel(int* __restrict__ row_ptr, int* __restrict__ cursor,
                             const int* __restrict__ bsum, int N, int totE)
{
    int i = blockIdx.x * blockDim.x + threadIdx.x;
    int stride = gridDim.x * blockDim.x;
    for (; i < N; i += stride) {
        int v = row_ptr[i] + bsum[i >> 11];
        row_ptr[i] = v;
        cursor[i]  = v;
    }
    if (blockIdx.x == 0 && threadIdx.x == 0) row_ptr[N] = totE;
}

__global__ void build_kernel(
    const int* __restrict__ s0, const int* __restrict__ d0,
    const int* __restrict__ s1, const int* __restrict__ d1,
    const int* __restrict__ s2, const int* __restrict__ d2,
    int* __restrict__ cursor, int* __restrict__ dstc_csr, int E, int N)
{
    const int cls8 = blockIdx.x & 7;
    const int bidx = blockIdx.x >> 3;
    const int nb   = gridDim.x >> 3;
    const int rng  = (N + 7) >> 3;
    const int lo = cls8 * rng, hi = min(lo + rng, N);
    const int tot = 3 * E;
    for (int i = bidx * blockDim.x + threadIdx.x; i < tot; i += nb * blockDim.x) {
        int src;
        if (i < E)          src = s0[i];
        else if (i < 2 * E) src = s1[i - E];
        else                src = s2[i - 2 * E];
        if (src < lo || src >= hi) continue;        // dst loaded only if ours
        int dst, cls;
        if (i < E)          { dst = d0[i];         cls = 0; }
        else if (i < 2 * E) { dst = d1[i - E];     cls = 1; }
        else                { dst = d2[i - 2 * E]; cls = 2; }
        int pos = atomicAdd(&cursor[src], 1);
        dstc_csr[pos] = dst | (cls << 24);
    }
}

// ---------------- fused per-node sim: raw w + per-node scale ----------------
// One 64-lane wave per node: 4 edge-subgroups x 16 lanes, f16 rows + fdot2.
__global__ void node_sim_kernel(const _Float16* __restrict__ hnf,
    const int* __restrict__ row_ptr, const int* __restrict__ dstc_csr,
    const float* __restrict__ ew0, const float* __restrict__ ew1,
    const float* __restrict__ ew2, float2* __restrict__ wd_csr,
    float* __restrict__ scl, int N)
{
    const int gtid = blockIdx.x * blockDim.x + threadIdx.x;
    const int lane = threadIdx.x & 63;
    const int sg   = lane >> 4;
    const int l16  = lane & 15;
    const int wv   = gtid >> 6;
    const int nwv  = (gridDim.x * blockDim.x) >> 6;
    const float sg0 = 1.f / (1.f + expf(-ew0[0]));
    const float sg1 = 1.f / (1.f + expf(-ew1[0]));
    const float sg2 = 1.f / (1.f + expf(-ew2[0]));
    for (int n = wv; n < N; n += nwv) {
        const int beg = row_ptr[n], end = row_ptr[n + 1];
        const int deg = end - beg;
        if (deg == 0) { if (lane == 0) scl[n] = ALPHA_; continue; }
        H8 a;
        a.v = *(const h8*)&hnf[(size_t)n * 128 + l16 * 8];

        float total = 0.f;
#pragma unroll 2
        for (int k = sg; k < deg; k += 4) {
            int e = beg + k;
            int v = dstc_csr[e];
            int dst = v & 0xFFFFFF;
            H8 c;
            c.v = *(const h8*)&hnf[(size_t)dst * 128 + l16 * 8];
            float p = dot8(a, c, 0.f);
#pragma unroll
            for (int m = 1; m <= 8; m <<= 1) p += __shfl_xor(p, m);
            int cls = v >> 24;
            float w = ((cls == 0) ? sg0 : (cls == 1) ? sg1 : sg2) * p;
            total += w;
            if (((k >> 2) & 15) == l16) {
                float2 wd; wd.x = w; wd.y = __int_as_float(v);
                wd_csr[e] = wd;
            }
        }
        total += __shfl_xor(total, 16);
        total += __shfl_xor(total, 32);
        if (lane == 0)
            scl[n] = ALPHA_ * ((total > 0.f) ? 1.f / total : 1.f);
    }
}

// ---------------- init f32 -> f16 -------------------------------------------
__global__ void cvt_kernel(const float* __restrict__ init,
                           _Float16* __restrict__ outh, int M4)
{
    int i = blockIdx.x * blockDim.x + threadIdx.x;
    int stride = gridDim.x * blockDim.x;
    for (; i < M4; i += stride) {
        float4 v = ((const float4*)init)[i];
        h4 o;
        o[0] = (_Float16)v.x; o[1] = (_Float16)v.y;
        o[2] = (_Float16)v.z; o[3] = (_Float16)v.w;
        ((h4*)outh)[i] = o;
    }
}

// ---------------- propagation: out = scl*sum(w*cur[dst]) + 0.5*init ---------
// One wave per node, 4 edge-subgroups, class c = lane&15. cur/init in f16.
template<bool LAST>
__global__ void prop_kernel(const int* __restrict__ row_ptr,
    const float2* __restrict__ wd_csr, const float* __restrict__ scl,
    const _Float16* __restrict__ cur, const _Float16* __restrict__ inith,
    float* __restrict__ out32, _Float16* __restrict__ out16, int N)
{
    const int gtid = blockIdx.x * blockDim.x + threadIdx.x;
    const int lane = threadIdx.x & 63;
    const int sg   = lane >> 4;
    const int c    = lane & 15;
    const int wv   = gtid >> 6;
    const int nwv  = (gridDim.x * blockDim.x) >> 6;
    for (int n = wv; n < N; n += nwv) {
        int beg = row_ptr[n], end = row_ptr[n + 1];
        float acc = 0.f;
#pragma unroll 4
        for (int e = beg + sg; e < end; e += 4) {
            float2 wd = wd_csr[e];
            int d = __float_as_int(wd.y) & 0xFFFFFF;
            acc += wd.x * (float)cur[(size_t)d * 16 + c];
        }
        acc += __shfl_xor(acc, 16);
        acc += __shfl_xor(acc, 32);
        if (sg == 0) {
            float r = scl[n] * acc
                    + (1.f - ALPHA_) * (float)inith[(size_t)n * 16 + c];
            if (LAST) out32[(size_t)n * 16 + c] = r;
            else      out16[(size_t)n * 16 + c] = (_Float16)r;
        }
    }
}

extern "C" void kernel_launch(void* const* d_in, const int* in_sizes, int n_in,
                              void* d_out, int out_size, void* d_ws, size_t ws_size,
                              hipStream_t stream)
{
    const float* feat  = (const float*)d_in[0];
    const float* initl = (const float*)d_in[1];
    const float* W     = (const float*)d_in[2];
    const float* b     = (const float*)d_in[3];
    const float* gam   = (const float*)d_in[4];
    const float* bet   = (const float*)d_in[5];
    const float* ew0   = (const float*)d_in[6];
    const float* ew1   = (const float*)d_in[7];
    const float* ew2   = (const float*)d_in[8];
    const int* s0  = (const int*)d_in[9];
    const int* dd0 = (const int*)d_in[10];
    const int* s1  = (const int*)d_in[11];
    const int* dd1 = (const int*)d_in[12];
    const int* s2  = (const int*)d_in[13];
    const int* dd2 = (const int*)d_in[14];

    const int N = in_sizes[0] / DD;
    const int E = in_sizes[9];
    const int totE = 3 * E;
    float* out = (float*)d_out;

    char* ws = (char*)d_ws;
    size_t off = 0;
    auto alloc = [&](size_t bytes) -> void* {
        void* p = ws + off;
        off += (bytes + 255) & ~(size_t)255;
        return p;
    };
    _Float16* hnf     = (_Float16*)alloc((size_t)N * DD * 2);
    int*      cnt     = (int*)alloc((size_t)N * 4);
    int*      row_ptr = (int*)alloc((size_t)(N + 1) * 4);
    int*      cursor  = (int*)alloc((size_t)N * 4);
    int*      bsum    = (int*)alloc(4096);
    int*      dstc_csr= (int*)alloc((size_t)totE * 4);
    float2*   wd_csr  = (float2*)alloc((size_t)totE * 8);
    float*    scl     = (float*)alloc((size_t)N * 4);
    _Float16* inith   = (_Float16*)alloc((size_t)N * CC * 2);
    _Float16* curA    = (_Float16*)alloc((size_t)N * CC * 2);
    _Float16* curB    = (_Float16*)alloc((size_t)N * CC * 2);

    // 1) feature transform -> f16 normalized rows
    ft_kernel<<<512, 256, 0, stream>>>(feat, W, b, gam, bet, hnf, N);

    // 2) CSR build (counting sort by src), XCD-partitioned
    hipMemsetAsync(cnt, 0, (size_t)N * 4, stream);
    hist_kernel<<<8192, 256, 0, stream>>>(s0, s1, s2, cnt, E, N);
    const int nblk = (N + 2047) / 2048;
    scan1_kernel<<<nblk, 256, 0, stream>>>(cnt, row_ptr, bsum, N);
    scan2_kernel<<<1, 64, 0, stream>>>(bsum, nblk);
    scan3_kernel<<<256, 256, 0, stream>>>(row_ptr, cursor, bsum, N, totE);
    build_kernel<<<8192, 256, 0, stream>>>(s0, dd0, s1, dd1, s2, dd2,
                                           cursor, dstc_csr, E, N);

    // 3) fused edge weights (raw w) + per-node scale
    const int wblk = (N * 64 + 255) / 256;
    node_sim_kernel<<<wblk, 256, 0, stream>>>(hnf, row_ptr, dstc_csr,
                                              ew0, ew1, ew2, wd_csr, scl, N);

    // 4) init -> f16, then 5 propagation layers (ping-pong, race-free)
    cvt_kernel<<<256, 256, 0, stream>>>(initl, inith, N * CC / 4);
    const _Float16* cs = inith;
    _Float16* bufs[2] = { curA, curB };
    for (int layer = 0; layer < 4; ++layer) {
        _Float16* dst = bufs[layer & 1];
        prop_kernel<false><<<wblk, 256, 0, stream>>>(row_ptr, wd_csr, scl,
                                                     cs, inith, nullptr, dst, N);
        cs = dst;
    }
    prop_kernel<true><<<wblk, 256, 0, stream>>>(row_ptr, wd_csr, scl,
                                                cs, inith, out, nullptr, N);
}

// Round 7
// 546.696 us; speedup vs baseline: 7.5760x; 1.3940x over previous
//
#include <hip/hip_runtime.h>
#include <math.h>

#define DD 128
#define CC 16
#define ALPHA_ 0.5f
#define EPS_LN 1e-5f
#define EPS_COS 1e-8f

typedef _Float16 h2 __attribute__((ext_vector_type(2)));
typedef _Float16 h4 __attribute__((ext_vector_type(4)));
typedef _Float16 h8 __attribute__((ext_vector_type(8)));

union H8 { h8 v; h2 p[4]; };

__device__ __forceinline__ float dot8(const H8& a, const H8& c, float acc) {
#if __has_builtin(__builtin_amdgcn_fdot2)
#pragma unroll
    for (int q = 0; q < 4; ++q)
        acc = __builtin_amdgcn_fdot2(a.p[q], c.p[q], acc, false);
#else
#pragma unroll
    for (int q = 0; q < 4; ++q)
        acc += (float)a.p[q][0] * (float)c.p[q][0]
             + (float)a.p[q][1] * (float)c.p[q][1];
#endif
    return acc;
}

// ---------------- Kernel A: feature transform -> f16 L2-normalized rows ----
__global__ __launch_bounds__(256, 2) void ft_kernel(
    const float* __restrict__ feat, const float* __restrict__ W,
    const float* __restrict__ b, const float* __restrict__ gamma,
    const float* __restrict__ beta, _Float16* __restrict__ hnf, int N)
{
    __shared__ float4 Wl[128 * 32];   // 64 KB
    __shared__ float4 Fl[32 * 32];    // 16 KB

    const int tid = threadIdx.x;
    const int jq  = tid & 31;
    const int rq  = tid >> 5;

    const float4* Wg = (const float4*)W;
    for (int idx = tid; idx < 128 * 32; idx += 256) {
        int r = idx >> 5, kc = idx & 31;
        Wl[r * 32 + (kc ^ ((r >> 2) & 31))] = Wg[idx];
    }
    const float4 b4  = ((const float4*)b)[jq];
    const float4 g4  = ((const float4*)gamma)[jq];
    const float4 be4 = ((const float4*)beta)[jq];
    __syncthreads();

    const int iters = (N + 31) >> 5;
    for (int g = blockIdx.x; g < iters; g += gridDim.x) {
        const int row0 = g << 5;
        for (int t = 0; t < 4; ++t) {
            int idx = tid + t * 256;
            int r = idx >> 5;
            int grow = row0 + r;
            Fl[idx] = (grow < N) ? ((const float4*)feat)[(size_t)grow * 32 + (idx & 31)]
                                 : make_float4(0.f, 0.f, 0.f, 0.f);
        }
        __syncthreads();

        float acc[4][4];
#pragma unroll
        for (int r = 0; r < 4; ++r) {
            acc[r][0] = b4.x; acc[r][1] = b4.y; acc[r][2] = b4.z; acc[r][3] = b4.w;
        }
#pragma unroll 2
        for (int kc = 0; kc < 32; ++kc) {
            float4 wv[4], fv[4];
#pragma unroll
            for (int i = 0; i < 4; ++i)
                wv[i] = Wl[(4 * jq + i) * 32 + (kc ^ jq)];
#pragma unroll
            for (int i = 0; i < 4; ++i)
                fv[i] = Fl[(4 * rq + i) * 32 + kc];
#pragma unroll
            for (int r = 0; r < 4; ++r) {
#pragma unroll
                for (int c = 0; c < 4; ++c) {
                    acc[r][c] += fv[r].x * wv[c].x + fv[r].y * wv[c].y
                               + fv[r].z * wv[c].z + fv[r].w * wv[c].w;
                }
            }
        }
        __syncthreads();

#pragma unroll
        for (int r = 0; r < 4; ++r) {
            float s  = acc[r][0] + acc[r][1] + acc[r][2] + acc[r][3];
            float s2 = acc[r][0] * acc[r][0] + acc[r][1] * acc[r][1]
                     + acc[r][2] * acc[r][2] + acc[r][3] * acc[r][3];
#pragma unroll
            for (int m = 1; m <= 16; m <<= 1) {
                s  += __shfl_xor(s, m);
                s2 += __shfl_xor(s2, m);
            }
            float mu   = s * (1.f / 128.f);
            float var  = s2 * (1.f / 128.f) - mu * mu;
            float rstd = rsqrtf(var + EPS_LN);

            float v0 = fmaxf((acc[r][0] - mu) * rstd * g4.x + be4.x, 0.f);
            float v1 = fmaxf((acc[r][1] - mu) * rstd * g4.y + be4.y, 0.f);
            float v2 = fmaxf((acc[r][2] - mu) * rstd * g4.z + be4.z, 0.f);
            float v3 = fmaxf((acc[r][3] - mu) * rstd * g4.w + be4.w, 0.f);

            float nsq = v0 * v0 + v1 * v1 + v2 * v2 + v3 * v3;
#pragma unroll
            for (int m = 1; m <= 16; m <<= 1) nsq += __shfl_xor(nsq, m);
            float inv = 1.f / fmaxf(sqrtf(nsq), EPS_COS);

            int grow = row0 + 4 * rq + r;
            if (grow < N) {
                h4 st;
                st[0] = (_Float16)(v0 * inv); st[1] = (_Float16)(v1 * inv);
                st[2] = (_Float16)(v2 * inv); st[3] = (_Float16)(v3 * inv);
                *(h4*)&hnf[(size_t)grow * 128 + jq * 4] = st;
            }
        }
    }
}

// ================= CSR build: 2-level bucket sort ===========================
// Buckets of 256 nodes (bucket = src>>8). Stage word packs
// dst[0:17) | cls[17:19) | lsrc[19:27)  (dst<2^17, lsrc<256).

// ---- pass 0: bucket counts (LDS histogram per block, one atomic/bucket) ----
__global__ void bcount_kernel(const int* __restrict__ s0, const int* __restrict__ s1,
                              const int* __restrict__ s2, int* __restrict__ gcnt,
                              int E, int NB)
{
    __shared__ int cnt[512];
    const int tid = threadIdx.x;
    for (int i = tid; i < NB; i += 256) cnt[i] = 0;
    __syncthreads();
    const int tot = 3 * E;
    const int chunk = (tot + gridDim.x - 1) / gridDim.x;
    const int lo = blockIdx.x * chunk, hi = min(lo + chunk, tot);
    for (int i = lo + tid; i < hi; i += 256) {
        int src = (i < E) ? s0[i] : (i < 2 * E) ? s1[i - E] : s2[i - 2 * E];
        atomicAdd(&cnt[src >> 8], 1);
    }
    __syncthreads();
    for (int i = tid; i < NB; i += 256)
        if (cnt[i]) atomicAdd(&gcnt[i], cnt[i]);
}

// ---- pass 0b: scan bucket counts (1 block) ---------------------------------
__global__ void bscan_kernel(const int* __restrict__ gcnt, int* __restrict__ bbase,
                             int* __restrict__ gcur, int NB, int totE)
{
    __shared__ int wsum[4];
    const int t = threadIdx.x;
    const int lane = t & 63;
    int a0 = (2 * t     < NB) ? gcnt[2 * t]     : 0;
    int a1 = (2 * t + 1 < NB) ? gcnt[2 * t + 1] : 0;
    int ts = a0 + a1;
    int v = ts;
#pragma unroll
    for (int m = 1; m <= 32; m <<= 1) {
        int u = __shfl_up(v, m);
        if (lane >= m) v += u;
    }
    if (lane == 63) wsum[t >> 6] = v;
    __syncthreads();
    int woff = 0;
    for (int w = 0; w < (t >> 6); ++w) woff += wsum[w];
    int excl = woff + v - ts;
    if (2 * t < NB)     { bbase[2 * t]     = excl;      gcur[2 * t]     = excl; }
    if (2 * t + 1 < NB) { bbase[2 * t + 1] = excl + a0; gcur[2 * t + 1] = excl + a0; }
    if (t == 0) bbase[NB] = totE;
}

// ---- pass 1: partition edges into bucket regions (batched reservations) ----
__global__ void bpart_kernel(
    const int* __restrict__ s0, const int* __restrict__ d0,
    const int* __restrict__ s1, const int* __restrict__ d1,
    const int* __restrict__ s2, const int* __restrict__ d2,
    int* __restrict__ gcur, unsigned* __restrict__ stage, int E, int NB)
{
    __shared__ int cnt[512];
    __shared__ int rbase[512];
    const int tid = threadIdx.x;
    for (int i = tid; i < NB; i += 256) cnt[i] = 0;
    __syncthreads();
    const int tot = 3 * E;
    const int chunk = (tot + gridDim.x - 1) / gridDim.x;
    const int lo = blockIdx.x * chunk, hi = min(lo + chunk, tot);
    for (int i = lo + tid; i < hi; i += 256) {
        int src = (i < E) ? s0[i] : (i < 2 * E) ? s1[i - E] : s2[i - 2 * E];
        atomicAdd(&cnt[src >> 8], 1);
    }
    __syncthreads();
    for (int i = tid; i < NB; i += 256) {
        int c = cnt[i];
        rbase[i] = c ? atomicAdd(&gcur[i], c) : 0;
        cnt[i] = 0;          // reuse as within-block offset
    }
    __syncthreads();
    for (int i = lo + tid; i < hi; i += 256) {
        int src, dst, cls;
        if (i < E)          { src = s0[i];         dst = d0[i];         cls = 0; }
        else if (i < 2 * E) { src = s1[i - E];     dst = d1[i - E];     cls = 1; }
        else                { src = s2[i - 2 * E]; dst = d2[i - 2 * E]; cls = 2; }
        int b = src >> 8;
        int pos = rbase[b] + atomicAdd(&cnt[b], 1);
        stage[pos] = (unsigned)dst | ((unsigned)cls << 17) | ((unsigned)(src & 255) << 19);
    }
}

// ---- pass 2: per-bucket local sort -> row_ptr + final CSR (L2-hot, 1 write)-
__global__ void csrfin_kernel(const unsigned* __restrict__ stage,
                              const int* __restrict__ bbase,
                              int* __restrict__ row_ptr, int* __restrict__ dstc_csr,
                              int N, int totE)
{
    __shared__ int cnt[256];
    __shared__ int wsum[4];
    const int b = blockIdx.x;
    const int t = threadIdx.x;
    const int lane = t & 63;
    const int lo = b << 8;
    const int base = bbase[b];
    const int m = bbase[b + 1] - base;

    cnt[t] = 0;
    __syncthreads();
    for (int i = t; i < m; i += 256)
        atomicAdd(&cnt[(stage[base + i] >> 19) & 255], 1);
    __syncthreads();
    int c = cnt[t];
    int v = c;
#pragma unroll
    for (int mm = 1; mm <= 32; mm <<= 1) {
        int u = __shfl_up(v, mm);
        if (lane >= mm) v += u;
    }
    if (lane == 63) wsum[t >> 6] = v;
    __syncthreads();
    int woff = 0;
    for (int w = 0; w < (t >> 6); ++w) woff += wsum[w];
    int excl = woff + v - c;
    if (lo + t < N) row_ptr[lo + t] = base + excl;
    if (b == 0 && t == 0) row_ptr[N] = totE;
    __syncthreads();     // everyone done reading cnt as counts
    cnt[t] = base + excl;  // now a cursor
    __syncthreads();
    for (int i = t; i < m; i += 256) {
        unsigned v2 = stage[base + i];
        int pos = atomicAdd(&cnt[(v2 >> 19) & 255], 1);
        dstc_csr[pos] = (int)(v2 & 0x1FFFF) | (int)(((v2 >> 17) & 3) << 24);
    }
}

// ---------------- fused per-node sim: raw w + per-node scale ----------------
// One 64-lane wave per node: 4 edge-subgroups x 16 lanes, f16 rows + fdot2.
__global__ void node_sim_kernel(const _Float16* __restrict__ hnf,
    const int* __restrict__ row_ptr, const int* __restrict__ dstc_csr,
    const float* __restrict__ ew0, const float* __restrict__ ew1,
    const float* __restrict__ ew2, float2* __restrict__ wd_csr,
    float* __restrict__ scl, int N)
{
    const int gtid = blockIdx.x * blockDim.x + threadIdx.x;
    const int lane = threadIdx.x & 63;
    const int sg   = lane >> 4;
    const int l16  = lane & 15;
    const int wv   = gtid >> 6;
    const int nwv  = (gridDim.x * blockDim.x) >> 6;
    const float sg0 = 1.f / (1.f + expf(-ew0[0]));
    const float sg1 = 1.f / (1.f + expf(-ew1[0]));
    const float sg2 = 1.f / (1.f + expf(-ew2[0]));
    for (int n = wv; n < N; n += nwv) {
        const int beg = row_ptr[n], end = row_ptr[n + 1];
        const int deg = end - beg;
        if (deg == 0) { if (lane == 0) scl[n] = ALPHA_; continue; }
        H8 a;
        a.v = *(const h8*)&hnf[(size_t)n * 128 + l16 * 8];

        float total = 0.f;
#pragma unroll 2
        for (int k = sg; k < deg; k += 4) {
            int e = beg + k;
            int v = dstc_csr[e];
            int dst = v & 0xFFFFFF;
            H8 c;
            c.v = *(const h8*)&hnf[(size_t)dst * 128 + l16 * 8];
            float p = dot8(a, c, 0.f);
#pragma unroll
            for (int m = 1; m <= 8; m <<= 1) p += __shfl_xor(p, m);
            int cls = v >> 24;
            float w = ((cls == 0) ? sg0 : (cls == 1) ? sg1 : sg2) * p;
            total += w;
            if (((k >> 2) & 15) == l16) {
                float2 wd; wd.x = w; wd.y = __int_as_float(v);
                wd_csr[e] = wd;
            }
        }
        total += __shfl_xor(total, 16);
        total += __shfl_xor(total, 32);
        if (lane == 0)
            scl[n] = ALPHA_ * ((total > 0.f) ? 1.f / total : 1.f);
    }
}

// ---------------- init f32 -> f16 -------------------------------------------
__global__ void cvt_kernel(const float* __restrict__ init,
                           _Float16* __restrict__ outh, int M4)
{
    int i = blockIdx.x * blockDim.x + threadIdx.x;
    int stride = gridDim.x * blockDim.x;
    for (; i < M4; i += stride) {
        float4 v = ((const float4*)init)[i];
        h4 o;
        o[0] = (_Float16)v.x; o[1] = (_Float16)v.y;
        o[2] = (_Float16)v.z; o[3] = (_Float16)v.w;
        ((h4*)outh)[i] = o;
    }
}

// ---------------- propagation: out = scl*sum(w*cur[dst]) + 0.5*init ---------
// One wave per node, 8 edge-subgroups x 8 lanes; lane holds classes
// {2*c8, 2*c8+1} via h2 loads -> 8 edges in flight per wave.
template<bool LAST>
__global__ void prop_kernel(const int* __restrict__ row_ptr,
    const float2* __restrict__ wd_csr, const float* __restrict__ scl,
    const _Float16* __restrict__ cur, const _Float16* __restrict__ inith,
    float* __restrict__ out32, _Float16* __restrict__ out16, int N)
{
    const int gtid = blockIdx.x * blockDim.x + threadIdx.x;
    const int lane = threadIdx.x & 63;
    const int sg   = lane >> 3;
    const int c8   = lane & 7;
    const int wv   = gtid >> 6;
    const int nwv  = (gridDim.x * blockDim.x) >> 6;
    for (int n = wv; n < N; n += nwv) {
        int beg = row_ptr[n], end = row_ptr[n + 1];
        float ax = 0.f, ay = 0.f;
#pragma unroll 4
        for (int e = beg + sg; e < end; e += 8) {
            float2 wd = wd_csr[e];
            int d = __float_as_int(wd.y) & 0xFFFFFF;
            h2 cv = *(const h2*)&cur[(size_t)d * 16 + c8 * 2];
            ax += wd.x * (float)cv[0];
            ay += wd.x * (float)cv[1];
        }
#pragma unroll
        for (int m = 8; m <= 32; m <<= 1) {
            ax += __shfl_xor(ax, m);
            ay += __shfl_xor(ay, m);
        }
        if (sg == 0) {
            float sc = scl[n];
            h2 iv = *(const h2*)&inith[(size_t)n * 16 + c8 * 2];
            float r0 = sc * ax + (1.f - ALPHA_) * (float)iv[0];
            float r1 = sc * ay + (1.f - ALPHA_) * (float)iv[1];
            if (LAST) {
                float2 st; st.x = r0; st.y = r1;
                *(float2*)&out32[(size_t)n * 16 + c8 * 2] = st;
            } else {
                h2 st; st[0] = (_Float16)r0; st[1] = (_Float16)r1;
                *(h2*)&out16[(size_t)n * 16 + c8 * 2] = st;
            }
        }
    }
}

extern "C" void kernel_launch(void* const* d_in, const int* in_sizes, int n_in,
                              void* d_out, int out_size, void* d_ws, size_t ws_size,
                              hipStream_t stream)
{
    const float* feat  = (const float*)d_in[0];
    const float* initl = (const float*)d_in[1];
    const float* W     = (const float*)d_in[2];
    const float* b     = (const float*)d_in[3];
    const float* gam   = (const float*)d_in[4];
    const float* bet   = (const float*)d_in[5];
    const float* ew0   = (const float*)d_in[6];
    const float* ew1   = (const float*)d_in[7];
    const float* ew2   = (const float*)d_in[8];
    const int* s0  = (const int*)d_in[9];
    const int* dd0 = (const int*)d_in[10];
    const int* s1  = (const int*)d_in[11];
    const int* dd1 = (const int*)d_in[12];
    const int* s2  = (const int*)d_in[13];
    const int* dd2 = (const int*)d_in[14];

    const int N = in_sizes[0] / DD;
    const int E = in_sizes[9];
    const int totE = 3 * E;
    const int NB = (N + 255) >> 8;   // buckets of 256 nodes (<=512 assumed)
    float* out = (float*)d_out;

    char* ws = (char*)d_ws;
    size_t off = 0;
    auto alloc = [&](size_t bytes) -> void* {
        void* p = ws + off;
        off += (bytes + 255) & ~(size_t)255;
        return p;
    };
    _Float16* hnf     = (_Float16*)alloc((size_t)N * DD * 2);
    int*      gcnt    = (int*)alloc((size_t)(NB + 1) * 4);
    int*      bbase   = (int*)alloc((size_t)(NB + 1) * 4);
    int*      gcur    = (int*)alloc((size_t)(NB + 1) * 4);
    int*      row_ptr = (int*)alloc((size_t)(N + 1) * 4);
    unsigned* stage   = (unsigned*)alloc((size_t)totE * 4);
    int*      dstc_csr= (int*)alloc((size_t)totE * 4);
    float2*   wd_csr  = (float2*)alloc((size_t)totE * 8);
    float*    scl     = (float*)alloc((size_t)N * 4);
    _Float16* inith   = (_Float16*)alloc((size_t)N * CC * 2);
    _Float16* curA    = (_Float16*)alloc((size_t)N * CC * 2);
    _Float16* curB    = (_Float16*)alloc((size_t)N * CC * 2);

    // 1) feature transform -> f16 normalized rows
    ft_kernel<<<512, 256, 0, stream>>>(feat, W, b, gam, bet, hnf, N);

    // 2) CSR build: bucket count -> scan -> partition -> per-bucket finalize
    hipMemsetAsync(gcnt, 0, (size_t)NB * 4, stream);
    bcount_kernel<<<NB, 256, 0, stream>>>(s0, s1, s2, gcnt, E, NB);
    bscan_kernel<<<1, 256, 0, stream>>>(gcnt, bbase, gcur, NB, totE);
    bpart_kernel<<<NB, 256, 0, stream>>>(s0, dd0, s1, dd1, s2, dd2,
                                         gcur, stage, E, NB);
    csrfin_kernel<<<NB, 256, 0, stream>>>(stage, bbase, row_ptr, dstc_csr, N, totE);

    // 3) fused edge weights (raw w) + per-node scale
    const int wblk = (N * 64 + 255) / 256;
    node_sim_kernel<<<wblk, 256, 0, stream>>>(hnf, row_ptr, dstc_csr,
                                              ew0, ew1, ew2, wd_csr, scl, N);

    // 4) init -> f16, then 5 propagation layers (ping-pong, race-free)
    cvt_kernel<<<256, 256, 0, stream>>>(initl, inith, N * CC / 4);
    const _Float16* cs = inith;
    _Float16* bufs[2] = { curA, curB };
    for (int layer = 0; layer < 4; ++layer) {
        _Float16* dst = bufs[layer & 1];
        prop_kernel<false><<<wblk, 256, 0, stream>>>(row_ptr, wd_csr, scl,
                                                     cs, inith, nullptr, dst, N);
        cs = dst;
    }
    prop_kernel<true><<<wblk, 256, 0, stream>>>(row_ptr, wd_csr, scl,
                                                cs, inith, out, nullptr, N);
}

// Round 8
// 488.095 us; speedup vs baseline: 8.4856x; 1.1201x over previous
//
#include <hip/hip_runtime.h>
#include <math.h>

#define DD 128
#define CC 16
#define ALPHA_ 0.5f
#define EPS_LN 1e-5f
#define EPS_COS 1e-8f

typedef _Float16 h2 __attribute__((ext_vector_type(2)));
typedef _Float16 h4 __attribute__((ext_vector_type(4)));
typedef _Float16 h8 __attribute__((ext_vector_type(8)));
typedef _Float16 f16x8 __attribute__((ext_vector_type(8)));
typedef float f32x4 __attribute__((ext_vector_type(4)));

union H8 { h8 v; h2 p[4]; };

__device__ __forceinline__ float dot8(const H8& a, const H8& c, float acc) {
#if __has_builtin(__builtin_amdgcn_fdot2)
#pragma unroll
    for (int q = 0; q < 4; ++q)
        acc = __builtin_amdgcn_fdot2(a.p[q], c.p[q], acc, false);
#else
#pragma unroll
    for (int q = 0; q < 4; ++q)
        acc += (float)a.p[q][0] * (float)c.p[q][0]
             + (float)a.p[q][1] * (float)c.p[q][1];
#endif
    return acc;
}

// ---------------- Kernel A: feature transform via MFMA ----------------------
// Computes h^T: D[j][i] = sum_k W[j][k] * feat[i][k] with mfma_f32_16x16x32_f16.
// A = W (hoisted fully into 128 VGPRs/lane-frags), B = feat tile (16 nodes).
// C/D layout (verified m89): col = lane&15 -> node i, row = (lane>>4)*4+r -> j.
// So each lane owns ONE node: LN/L2norm reduce = shfl_xor(16|32); stores are
// contiguous h4 (8B) at j = jt*16 + g*4.
__global__ __launch_bounds__(256, 2) void ft_mfma_kernel(
    const float* __restrict__ feat, const float* __restrict__ W,
    const float* __restrict__ bias, const float* __restrict__ gamma,
    const float* __restrict__ beta, _Float16* __restrict__ hnf, int N)
{
    const int lane = threadIdx.x & 63;
    const int c16  = lane & 15;   // node within tile (D col)
    const int g    = lane >> 4;   // k-subgroup / j-row quad
    const int wv   = (blockIdx.x * (int)blockDim.x + (int)threadIdx.x) >> 6;
    const int nwv  = ((int)gridDim.x * (int)blockDim.x) >> 6;

    // Hoist W (A operand): wf[jt][s] = W[jt*16+c16][s*32 + g*8 .. +8]  (f16)
    f16x8 wf[8][4];
#pragma unroll
    for (int jt = 0; jt < 8; ++jt) {
        const float* wr = W + (size_t)(jt * 16 + c16) * 128 + g * 8;
#pragma unroll
        for (int s = 0; s < 4; ++s) {
            float4 lo = *(const float4*)(wr + s * 32);
            float4 hi = *(const float4*)(wr + s * 32 + 4);
            f16x8 f;
            f[0] = (_Float16)lo.x; f[1] = (_Float16)lo.y;
            f[2] = (_Float16)lo.z; f[3] = (_Float16)lo.w;
            f[4] = (_Float16)hi.x; f[5] = (_Float16)hi.y;
            f[6] = (_Float16)hi.z; f[7] = (_Float16)hi.w;
            wf[jt][s] = f;
        }
    }

    const int ntiles = (N + 15) >> 4;
    for (int t = wv; t < ntiles; t += nwv) {
        const int i = (t << 4) + c16;
        const float* fr = feat + (size_t)min(i, N - 1) * 128 + g * 8;
        f16x8 bf[4];
#pragma unroll
        for (int s = 0; s < 4; ++s) {
            float4 lo = *(const float4*)(fr + s * 32);
            float4 hi = *(const float4*)(fr + s * 32 + 4);
            f16x8 f;
            f[0] = (_Float16)lo.x; f[1] = (_Float16)lo.y;
            f[2] = (_Float16)lo.z; f[3] = (_Float16)lo.w;
            f[4] = (_Float16)hi.x; f[5] = (_Float16)hi.y;
            f[6] = (_Float16)hi.z; f[7] = (_Float16)hi.w;
            bf[s] = f;
        }

        f32x4 acc[8] = {};
#pragma unroll
        for (int s = 0; s < 4; ++s)
#pragma unroll
            for (int jt = 0; jt < 8; ++jt)
                acc[jt] = __builtin_amdgcn_mfma_f32_16x16x32_f16(
                    wf[jt][s], bf[s], acc[jt], 0, 0, 0);

        // ---- epilogue: +bias, LayerNorm, ReLU, L2-normalize, f16 store ----
        float s1 = 0.f, s2 = 0.f;
#pragma unroll
        for (int jt = 0; jt < 8; ++jt) {
            float4 bb = ((const float4*)bias)[jt * 4 + g];
            float h0 = acc[jt][0] + bb.x, h1 = acc[jt][1] + bb.y;
            float h2_ = acc[jt][2] + bb.z, h3 = acc[jt][3] + bb.w;
            acc[jt][0] = h0; acc[jt][1] = h1; acc[jt][2] = h2_; acc[jt][3] = h3;
            s1 += h0 + h1 + h2_ + h3;
            s2 += h0 * h0 + h1 * h1 + h2_ * h2_ + h3 * h3;
        }
        s1 += __shfl_xor(s1, 16); s1 += __shfl_xor(s1, 32);
        s2 += __shfl_xor(s2, 16); s2 += __shfl_xor(s2, 32);
        float mu   = s1 * (1.f / 128.f);
        float var  = s2 * (1.f / 128.f) - mu * mu;
        float rstd = rsqrtf(var + EPS_LN);

        float nsq = 0.f;
#pragma unroll
        for (int jt = 0; jt < 8; ++jt) {
            float4 gg = ((const float4*)gamma)[jt * 4 + g];
            float4 be = ((const float4*)beta)[jt * 4 + g];
            float v0 = fmaxf((acc[jt][0] - mu) * rstd * gg.x + be.x, 0.f);
            float v1 = fmaxf((acc[jt][1] - mu) * rstd * gg.y + be.y, 0.f);
            float v2 = fmaxf((acc[jt][2] - mu) * rstd * gg.z + be.z, 0.f);
            float v3 = fmaxf((acc[jt][3] - mu) * rstd * gg.w + be.w, 0.f);
            acc[jt][0] = v0; acc[jt][1] = v1; acc[jt][2] = v2; acc[jt][3] = v3;
            nsq += v0 * v0 + v1 * v1 + v2 * v2 + v3 * v3;
        }
        nsq += __shfl_xor(nsq, 16); nsq += __shfl_xor(nsq, 32);
        float inv = 1.f / fmaxf(sqrtf(nsq), EPS_COS);

        if (i < N) {
#pragma unroll
            for (int jt = 0; jt < 8; ++jt) {
                h4 st;
                st[0] = (_Float16)(acc[jt][0] * inv);
                st[1] = (_Float16)(acc[jt][1] * inv);
                st[2] = (_Float16)(acc[jt][2] * inv);
                st[3] = (_Float16)(acc[jt][3] * inv);
                *(h4*)&hnf[(size_t)i * 128 + jt * 16 + g * 4] = st;
            }
        }
    }
}

// ================= CSR build: 2-level bucket sort ===========================
// Buckets of 256 nodes (bucket = src>>8). Stage word packs
// dst[0:17) | cls[17:19) | lsrc[19:27)  (dst<2^17, lsrc<256).

__global__ void bcount_kernel(const int* __restrict__ s0, const int* __restrict__ s1,
                              const int* __restrict__ s2, int* __restrict__ gcnt,
                              int E, int NB)
{
    __shared__ int cnt[512];
    const int tid = threadIdx.x;
    for (int i = tid; i < NB; i += 256) cnt[i] = 0;
    __syncthreads();
    const int tot = 3 * E;
    const int chunk = (tot + gridDim.x - 1) / gridDim.x;
    const int lo = blockIdx.x * chunk, hi = min(lo + chunk, tot);
    for (int i = lo + tid; i < hi; i += 256) {
        int src = (i < E) ? s0[i] : (i < 2 * E) ? s1[i - E] : s2[i - 2 * E];
        atomicAdd(&cnt[src >> 8], 1);
    }
    __syncthreads();
    for (int i = tid; i < NB; i += 256)
        if (cnt[i]) atomicAdd(&gcnt[i], cnt[i]);
}

__global__ void bscan_kernel(const int* __restrict__ gcnt, int* __restrict__ bbase,
                             int* __restrict__ gcur, int NB, int totE)
{
    __shared__ int wsum[4];
    const int t = threadIdx.x;
    const int lane = t & 63;
    int a0 = (2 * t     < NB) ? gcnt[2 * t]     : 0;
    int a1 = (2 * t + 1 < NB) ? gcnt[2 * t + 1] : 0;
    int ts = a0 + a1;
    int v = ts;
#pragma unroll
    for (int m = 1; m <= 32; m <<= 1) {
        int u = __shfl_up(v, m);
        if (lane >= m) v += u;
    }
    if (lane == 63) wsum[t >> 6] = v;
    __syncthreads();
    int woff = 0;
    for (int w = 0; w < (t >> 6); ++w) woff += wsum[w];
    int excl = woff + v - ts;
    if (2 * t < NB)     { bbase[2 * t]     = excl;      gcur[2 * t]     = excl; }
    if (2 * t + 1 < NB) { bbase[2 * t + 1] = excl + a0; gcur[2 * t + 1] = excl + a0; }
    if (t == 0) bbase[NB] = totE;
}

__global__ void bpart_kernel(
    const int* __restrict__ s0, const int* __restrict__ d0,
    const int* __restrict__ s1, const int* __restrict__ d1,
    const int* __restrict__ s2, const int* __restrict__ d2,
    int* __restrict__ gcur, unsigned* __restrict__ stage, int E, int NB)
{
    __shared__ int cnt[512];
    __shared__ int rbase[512];
    const int tid = threadIdx.x;
    for (int i = tid; i < NB; i += 256) cnt[i] = 0;
    __syncthreads();
    const int tot = 3 * E;
    const int chunk = (tot + gridDim.x - 1) / gridDim.x;
    const int lo = blockIdx.x * chunk, hi = min(lo + chunk, tot);
    for (int i = lo + tid; i < hi; i += 256) {
        int src = (i < E) ? s0[i] : (i < 2 * E) ? s1[i - E] : s2[i - 2 * E];
        atomicAdd(&cnt[src >> 8], 1);
    }
    __syncthreads();
    for (int i = tid; i < NB; i += 256) {
        int c = cnt[i];
        rbase[i] = c ? atomicAdd(&gcur[i], c) : 0;
        cnt[i] = 0;          // reuse as within-block offset
    }
    __syncthreads();
    for (int i = lo + tid; i < hi; i += 256) {
        int src, dst, cls;
        if (i < E)          { src = s0[i];         dst = d0[i];         cls = 0; }
        else if (i < 2 * E) { src = s1[i - E];     dst = d1[i - E];     cls = 1; }
        else                { src = s2[i - 2 * E]; dst = d2[i - 2 * E]; cls = 2; }
        int b = src >> 8;
        int pos = rbase[b] + atomicAdd(&cnt[b], 1);
        stage[pos] = (unsigned)dst | ((unsigned)cls << 17) | ((unsigned)(src & 255) << 19);
    }
}

__global__ void csrfin_kernel(const unsigned* __restrict__ stage,
                              const int* __restrict__ bbase,
                              int* __restrict__ row_ptr, int* __restrict__ dstc_csr,
                              int N, int totE)
{
    __shared__ int cnt[256];
    __shared__ int wsum[4];
    const int b = blockIdx.x;
    const int t = threadIdx.x;
    const int lane = t & 63;
    const int lo = b << 8;
    const int base = bbase[b];
    const int m = bbase[b + 1] - base;

    cnt[t] = 0;
    __syncthreads();
    for (int i = t; i < m; i += 256)
        atomicAdd(&cnt[(stage[base + i] >> 19) & 255], 1);
    __syncthreads();
    int c = cnt[t];
    int v = c;
#pragma unroll
    for (int mm = 1; mm <= 32; mm <<= 1) {
        int u = __shfl_up(v, mm);
        if (lane >= mm) v += u;
    }
    if (lane == 63) wsum[t >> 6] = v;
    __syncthreads();
    int woff = 0;
    for (int w = 0; w < (t >> 6); ++w) woff += wsum[w];
    int excl = woff + v - c;
    if (lo + t < N) row_ptr[lo + t] = base + excl;
    if (b == 0 && t == 0) row_ptr[N] = totE;
    __syncthreads();     // everyone done reading cnt as counts
    cnt[t] = base + excl;  // now a cursor
    __syncthreads();
    for (int i = t; i < m; i += 256) {
        unsigned v2 = stage[base + i];
        int pos = atomicAdd(&cnt[(v2 >> 19) & 255], 1);
        dstc_csr[pos] = (int)(v2 & 0x1FFFF) | (int)(((v2 >> 17) & 3) << 24);
    }
}

// ---------------- fused per-node sim: raw w + per-node scale ----------------
__global__ void node_sim_kernel(const _Float16* __restrict__ hnf,
    const int* __restrict__ row_ptr, const int* __restrict__ dstc_csr,
    const float* __restrict__ ew0, const float* __restrict__ ew1,
    const float* __restrict__ ew2, float2* __restrict__ wd_csr,
    float* __restrict__ scl, int N)
{
    const int gtid = blockIdx.x * blockDim.x + threadIdx.x;
    const int lane = threadIdx.x & 63;
    const int sg   = lane >> 4;
    const int l16  = lane & 15;
    const int wv   = gtid >> 6;
    const int nwv  = (gridDim.x * blockDim.x) >> 6;
    const float sg0 = 1.f / (1.f + expf(-ew0[0]));
    const float sg1 = 1.f / (1.f + expf(-ew1[0]));
    const float sg2 = 1.f / (1.f + expf(-ew2[0]));
    for (int n = wv; n < N; n += nwv) {
        const int beg = row_ptr[n], end = row_ptr[n + 1];
        const int deg = end - beg;
        if (deg == 0) { if (lane == 0) scl[n] = ALPHA_; continue; }
        H8 a;
        a.v = *(const h8*)&hnf[(size_t)n * 128 + l16 * 8];

        float total = 0.f;
#pragma unroll 2
        for (int k = sg; k < deg; k += 4) {
            int e = beg + k;
            int v = dstc_csr[e];
            int dst = v & 0xFFFFFF;
            H8 c;
            c.v = *(const h8*)&hnf[(size_t)dst * 128 + l16 * 8];
            float p = dot8(a, c, 0.f);
#pragma unroll
            for (int m = 1; m <= 8; m <<= 1) p += __shfl_xor(p, m);
            int cls = v >> 24;
            float w = ((cls == 0) ? sg0 : (cls == 1) ? sg1 : sg2) * p;
            total += w;
            if (((k >> 2) & 15) == l16) {
                float2 wd; wd.x = w; wd.y = __int_as_float(v);
                wd_csr[e] = wd;
            }
        }
        total += __shfl_xor(total, 16);
        total += __shfl_xor(total, 32);
        if (lane == 0)
            scl[n] = ALPHA_ * ((total > 0.f) ? 1.f / total : 1.f);
    }
}

// ---------------- init f32 -> f16 -------------------------------------------
__global__ void cvt_kernel(const float* __restrict__ init,
                           _Float16* __restrict__ outh, int M4)
{
    int i = blockIdx.x * blockDim.x + threadIdx.x;
    int stride = gridDim.x * blockDim.x;
    for (; i < M4; i += stride) {
        float4 v = ((const float4*)init)[i];
        h4 o;
        o[0] = (_Float16)v.x; o[1] = (_Float16)v.y;
        o[2] = (_Float16)v.z; o[3] = (_Float16)v.w;
        ((h4*)outh)[i] = o;
    }
}

// ---------------- propagation: out = scl*sum(w*cur[dst]) + 0.5*init ---------
template<bool LAST>
__global__ void prop_kernel(const int* __restrict__ row_ptr,
    const float2* __restrict__ wd_csr, const float* __restrict__ scl,
    const _Float16* __restrict__ cur, const _Float16* __restrict__ inith,
    float* __restrict__ out32, _Float16* __restrict__ out16, int N)
{
    const int gtid = blockIdx.x * blockDim.x + threadIdx.x;
    const int lane = threadIdx.x & 63;
    const int sg   = lane >> 3;
    const int c8   = lane & 7;
    const int wv   = gtid >> 6;
    const int nwv  = (gridDim.x * blockDim.x) >> 6;
    for (int n = wv; n < N; n += nwv) {
        int beg = row_ptr[n], end = row_ptr[n + 1];
        float ax = 0.f, ay = 0.f;
#pragma unroll 4
        for (int e = beg + sg; e < end; e += 8) {
            float2 wd = wd_csr[e];
            int d = __float_as_int(wd.y) & 0xFFFFFF;
            h2 cv = *(const h2*)&cur[(size_t)d * 16 + c8 * 2];
            ax += wd.x * (float)cv[0];
            ay += wd.x * (float)cv[1];
        }
#pragma unroll
        for (int m = 8; m <= 32; m <<= 1) {
            ax += __shfl_xor(ax, m);
            ay += __shfl_xor(ay, m);
        }
        if (sg == 0) {
            float sc = scl[n];
            h2 iv = *(const h2*)&inith[(size_t)n * 16 + c8 * 2];
            float r0 = sc * ax + (1.f - ALPHA_) * (float)iv[0];
            float r1 = sc * ay + (1.f - ALPHA_) * (float)iv[1];
            if (LAST) {
                float2 st; st.x = r0; st.y = r1;
                *(float2*)&out32[(size_t)n * 16 + c8 * 2] = st;
            } else {
                h2 st; st[0] = (_Float16)r0; st[1] = (_Float16)r1;
                *(h2*)&out16[(size_t)n * 16 + c8 * 2] = st;
            }
        }
    }
}

extern "C" void kernel_launch(void* const* d_in, const int* in_sizes, int n_in,
                              void* d_out, int out_size, void* d_ws, size_t ws_size,
                              hipStream_t stream)
{
    const float* feat  = (const float*)d_in[0];
    const float* initl = (const float*)d_in[1];
    const float* W     = (const float*)d_in[2];
    const float* b     = (const float*)d_in[3];
    const float* gam   = (const float*)d_in[4];
    const float* bet   = (const float*)d_in[5];
    const float* ew0   = (const float*)d_in[6];
    const float* ew1   = (const float*)d_in[7];
    const float* ew2   = (const float*)d_in[8];
    const int* s0  = (const int*)d_in[9];
    const int* dd0 = (const int*)d_in[10];
    const int* s1  = (const int*)d_in[11];
    const int* dd1 = (const int*)d_in[12];
    const int* s2  = (const int*)d_in[13];
    const int* dd2 = (const int*)d_in[14];

    const int N = in_sizes[0] / DD;
    const int E = in_sizes[9];
    const int totE = 3 * E;
    const int NB = (N + 255) >> 8;   // buckets of 256 nodes (<=512 assumed)
    float* out = (float*)d_out;

    char* ws = (char*)d_ws;
    size_t off = 0;
    auto alloc = [&](size_t bytes) -> void* {
        void* p = ws + off;
        off += (bytes + 255) & ~(size_t)255;
        return p;
    };
    _Float16* hnf     = (_Float16*)alloc((size_t)N * DD * 2);
    int*      gcnt    = (int*)alloc((size_t)(NB + 1) * 4);
    int*      bbase   = (int*)alloc((size_t)(NB + 1) * 4);
    int*      gcur    = (int*)alloc((size_t)(NB + 1) * 4);
    int*      row_ptr = (int*)alloc((size_t)(N + 1) * 4);
    unsigned* stage   = (unsigned*)alloc((size_t)totE * 4);
    int*      dstc_csr= (int*)alloc((size_t)totE * 4);
    float2*   wd_csr  = (float2*)alloc((size_t)totE * 8);
    float*    scl     = (float*)alloc((size_t)N * 4);
    _Float16* inith   = (_Float16*)alloc((size_t)N * CC * 2);
    _Float16* curA    = (_Float16*)alloc((size_t)N * CC * 2);
    _Float16* curB    = (_Float16*)alloc((size_t)N * CC * 2);

    // 1) feature transform (MFMA) -> f16 normalized rows
    ft_mfma_kernel<<<512, 256, 0, stream>>>(feat, W, b, gam, bet, hnf, N);

    // 2) CSR build: bucket count -> scan -> partition -> per-bucket finalize
    hipMemsetAsync(gcnt, 0, (size_t)NB * 4, stream);
    bcount_kernel<<<NB, 256, 0, stream>>>(s0, s1, s2, gcnt, E, NB);
    bscan_kernel<<<1, 256, 0, stream>>>(gcnt, bbase, gcur, NB, totE);
    bpart_kernel<<<NB, 256, 0, stream>>>(s0, dd0, s1, dd1, s2, dd2,
                                         gcur, stage, E, NB);
    csrfin_kernel<<<NB, 256, 0, stream>>>(stage, bbase, row_ptr, dstc_csr, N, totE);

    // 3) fused edge weights (raw w) + per-node scale
    const int wblk = (N * 64 + 255) / 256;
    node_sim_kernel<<<wblk, 256, 0, stream>>>(hnf, row_ptr, dstc_csr,
                                              ew0, ew1, ew2, wd_csr, scl, N);

    // 4) init -> f16, then 5 propagation layers (ping-pong, race-free)
    cvt_kernel<<<256, 256, 0, stream>>>(initl, inith, N * CC / 4);
    const _Float16* cs = inith;
    _Float16* bufs[2] = { curA, curB };
    for (int layer = 0; layer < 4; ++layer) {
        _Float16* dst = bufs[layer & 1];
        prop_kernel<false><<<wblk, 256, 0, stream>>>(row_ptr, wd_csr, scl,
                                                     cs, inith, nullptr, dst, N);
        cs = dst;
    }
    prop_kernel<true><<<wblk, 256, 0, stream>>>(row_ptr, wd_csr, scl,
                                                cs, inith, out, nullptr, N);
}

// Round 9
// 479.307 us; speedup vs baseline: 8.6412x; 1.0183x over previous
//
#include <hip/hip_runtime.h>
#include <math.h>

#define DD 128
#define CC 16
#define ALPHA_ 0.5f
#define EPS_LN 1e-5f
#define EPS_COS 1e-8f

typedef _Float16 h2 __attribute__((ext_vector_type(2)));
typedef _Float16 h4 __attribute__((ext_vector_type(4)));
typedef _Float16 f16x8 __attribute__((ext_vector_type(8)));
typedef float f32x4 __attribute__((ext_vector_type(4)));

// ---------------- Kernel A: feature transform via MFMA ----------------------
// Computes h^T: D[j][i] = sum_k W[j][k]*feat[i][k], mfma_f32_16x16x32_f16.
// Layout empirically verified in round 8 on this chip.
__global__ __launch_bounds__(256, 2) void ft_mfma_kernel(
    const float* __restrict__ feat, const float* __restrict__ W,
    const float* __restrict__ bias, const float* __restrict__ gamma,
    const float* __restrict__ beta, _Float16* __restrict__ hnf, int N)
{
    const int lane = threadIdx.x & 63;
    const int c16  = lane & 15;
    const int g    = lane >> 4;
    const int wv   = (blockIdx.x * (int)blockDim.x + (int)threadIdx.x) >> 6;
    const int nwv  = ((int)gridDim.x * (int)blockDim.x) >> 6;

    f16x8 wf[8][4];
#pragma unroll
    for (int jt = 0; jt < 8; ++jt) {
        const float* wr = W + (size_t)(jt * 16 + c16) * 128 + g * 8;
#pragma unroll
        for (int s = 0; s < 4; ++s) {
            float4 lo = *(const float4*)(wr + s * 32);
            float4 hi = *(const float4*)(wr + s * 32 + 4);
            f16x8 f;
            f[0] = (_Float16)lo.x; f[1] = (_Float16)lo.y;
            f[2] = (_Float16)lo.z; f[3] = (_Float16)lo.w;
            f[4] = (_Float16)hi.x; f[5] = (_Float16)hi.y;
            f[6] = (_Float16)hi.z; f[7] = (_Float16)hi.w;
            wf[jt][s] = f;
        }
    }

    const int ntiles = (N + 15) >> 4;
    for (int t = wv; t < ntiles; t += nwv) {
        const int i = (t << 4) + c16;
        const float* fr = feat + (size_t)min(i, N - 1) * 128 + g * 8;
        f16x8 bf[4];
#pragma unroll
        for (int s = 0; s < 4; ++s) {
            float4 lo = *(const float4*)(fr + s * 32);
            float4 hi = *(const float4*)(fr + s * 32 + 4);
            f16x8 f;
            f[0] = (_Float16)lo.x; f[1] = (_Float16)lo.y;
            f[2] = (_Float16)lo.z; f[3] = (_Float16)lo.w;
            f[4] = (_Float16)hi.x; f[5] = (_Float16)hi.y;
            f[6] = (_Float16)hi.z; f[7] = (_Float16)hi.w;
            bf[s] = f;
        }

        f32x4 acc[8] = {};
#pragma unroll
        for (int s = 0; s < 4; ++s)
#pragma unroll
            for (int jt = 0; jt < 8; ++jt)
                acc[jt] = __builtin_amdgcn_mfma_f32_16x16x32_f16(
                    wf[jt][s], bf[s], acc[jt], 0, 0, 0);

        float s1 = 0.f, s2 = 0.f;
#pragma unroll
        for (int jt = 0; jt < 8; ++jt) {
            float4 bb = ((const float4*)bias)[jt * 4 + g];
            float h0 = acc[jt][0] + bb.x, h1 = acc[jt][1] + bb.y;
            float h2_ = acc[jt][2] + bb.z, h3 = acc[jt][3] + bb.w;
            acc[jt][0] = h0; acc[jt][1] = h1; acc[jt][2] = h2_; acc[jt][3] = h3;
            s1 += h0 + h1 + h2_ + h3;
            s2 += h0 * h0 + h1 * h1 + h2_ * h2_ + h3 * h3;
        }
        s1 += __shfl_xor(s1, 16); s1 += __shfl_xor(s1, 32);
        s2 += __shfl_xor(s2, 16); s2 += __shfl_xor(s2, 32);
        float mu   = s1 * (1.f / 128.f);
        float var  = s2 * (1.f / 128.f) - mu * mu;
        float rstd = rsqrtf(var + EPS_LN);

        float nsq = 0.f;
#pragma unroll
        for (int jt = 0; jt < 8; ++jt) {
            float4 gg = ((const float4*)gamma)[jt * 4 + g];
            float4 be = ((const float4*)beta)[jt * 4 + g];
            float v0 = fmaxf((acc[jt][0] - mu) * rstd * gg.x + be.x, 0.f);
            float v1 = fmaxf((acc[jt][1] - mu) * rstd * gg.y + be.y, 0.f);
            float v2 = fmaxf((acc[jt][2] - mu) * rstd * gg.z + be.z, 0.f);
            float v3 = fmaxf((acc[jt][3] - mu) * rstd * gg.w + be.w, 0.f);
            acc[jt][0] = v0; acc[jt][1] = v1; acc[jt][2] = v2; acc[jt][3] = v3;
            nsq += v0 * v0 + v1 * v1 + v2 * v2 + v3 * v3;
        }
        nsq += __shfl_xor(nsq, 16); nsq += __shfl_xor(nsq, 32);
        float inv = 1.f / fmaxf(sqrtf(nsq), EPS_COS);

        if (i < N) {
#pragma unroll
            for (int jt = 0; jt < 8; ++jt) {
                h4 st;
                st[0] = (_Float16)(acc[jt][0] * inv);
                st[1] = (_Float16)(acc[jt][1] * inv);
                st[2] = (_Float16)(acc[jt][2] * inv);
                st[3] = (_Float16)(acc[jt][3] * inv);
                *(h4*)&hnf[(size_t)i * 128 + jt * 16 + g * 4] = st;
            }
        }
    }
}

// ================= CSR build: 2-level bucket sort ===========================
__global__ void bcount_kernel(const int* __restrict__ s0, const int* __restrict__ s1,
                              const int* __restrict__ s2, int* __restrict__ gcnt,
                              int E, int NB)
{
    __shared__ int cnt[512];
    const int tid = threadIdx.x;
    for (int i = tid; i < NB; i += 256) cnt[i] = 0;
    __syncthreads();
    const int tot = 3 * E;
    const int chunk = (tot + gridDim.x - 1) / gridDim.x;
    const int lo = blockIdx.x * chunk, hi = min(lo + chunk, tot);
    for (int i = lo + tid; i < hi; i += 256) {
        int src = (i < E) ? s0[i] : (i < 2 * E) ? s1[i - E] : s2[i - 2 * E];
        atomicAdd(&cnt[src >> 8], 1);
    }
    __syncthreads();
    for (int i = tid; i < NB; i += 256)
        if (cnt[i]) atomicAdd(&gcnt[i], cnt[i]);
}

__global__ void bscan_kernel(const int* __restrict__ gcnt, int* __restrict__ bbase,
                             int* __restrict__ gcur, int NB, int totE)
{
    __shared__ int wsum[4];
    const int t = threadIdx.x;
    const int lane = t & 63;
    int a0 = (2 * t     < NB) ? gcnt[2 * t]     : 0;
    int a1 = (2 * t + 1 < NB) ? gcnt[2 * t + 1] : 0;
    int ts = a0 + a1;
    int v = ts;
#pragma unroll
    for (int m = 1; m <= 32; m <<= 1) {
        int u = __shfl_up(v, m);
        if (lane >= m) v += u;
    }
    if (lane == 63) wsum[t >> 6] = v;
    __syncthreads();
    int woff = 0;
    for (int w = 0; w < (t >> 6); ++w) woff += wsum[w];
    int excl = woff + v - ts;
    if (2 * t < NB)     { bbase[2 * t]     = excl;      gcur[2 * t]     = excl; }
    if (2 * t + 1 < NB) { bbase[2 * t + 1] = excl + a0; gcur[2 * t + 1] = excl + a0; }
    if (t == 0) bbase[NB] = totE;
}

__global__ void bpart_kernel(
    const int* __restrict__ s0, const int* __restrict__ d0,
    const int* __restrict__ s1, const int* __restrict__ d1,
    const int* __restrict__ s2, const int* __restrict__ d2,
    int* __restrict__ gcur, unsigned* __restrict__ stage, int E, int NB)
{
    __shared__ int cnt[512];
    __shared__ int rbase[512];
    const int tid = threadIdx.x;
    for (int i = tid; i < NB; i += 256) cnt[i] = 0;
    __syncthreads();
    const int tot = 3 * E;
    const int chunk = (tot + gridDim.x - 1) / gridDim.x;
    const int lo = blockIdx.x * chunk, hi = min(lo + chunk, tot);
    for (int i = lo + tid; i < hi; i += 256) {
        int src = (i < E) ? s0[i] : (i < 2 * E) ? s1[i - E] : s2[i - 2 * E];
        atomicAdd(&cnt[src >> 8], 1);
    }
    __syncthreads();
    for (int i = tid; i < NB; i += 256) {
        int c = cnt[i];
        rbase[i] = c ? atomicAdd(&gcur[i], c) : 0;
        cnt[i] = 0;
    }
    __syncthreads();
    for (int i = lo + tid; i < hi; i += 256) {
        int src, dst, cls;
        if (i < E)          { src = s0[i];         dst = d0[i];         cls = 0; }
        else if (i < 2 * E) { src = s1[i - E];     dst = d1[i - E];     cls = 1; }
        else                { src = s2[i - 2 * E]; dst = d2[i - 2 * E]; cls = 2; }
        int b = src >> 8;
        int pos = rbase[b] + atomicAdd(&cnt[b], 1);
        stage[pos] = (unsigned)dst | ((unsigned)cls << 17) | ((unsigned)(src & 255) << 19);
    }
}

__global__ void csrfin_kernel(const unsigned* __restrict__ stage,
                              const int* __restrict__ bbase,
                              int* __restrict__ row_ptr, int* __restrict__ dstc_csr,
                              int N, int totE)
{
    __shared__ int cnt[256];
    __shared__ int wsum[4];
    const int b = blockIdx.x;
    const int t = threadIdx.x;
    const int lane = t & 63;
    const int lo = b << 8;
    const int base = bbase[b];
    const int m = bbase[b + 1] - base;

    cnt[t] = 0;
    __syncthreads();
    for (int i = t; i < m; i += 256)
        atomicAdd(&cnt[(stage[base + i] >> 19) & 255], 1);
    __syncthreads();
    int c = cnt[t];
    int v = c;
#pragma unroll
    for (int mm = 1; mm <= 32; mm <<= 1) {
        int u = __shfl_up(v, mm);
        if (lane >= mm) v += u;
    }
    if (lane == 63) wsum[t >> 6] = v;
    __syncthreads();
    int woff = 0;
    for (int w = 0; w < (t >> 6); ++w) woff += wsum[w];
    int excl = woff + v - c;
    if (lo + t < N) row_ptr[lo + t] = base + excl;
    if (b == 0 && t == 0) row_ptr[N] = totE;
    __syncthreads();
    cnt[t] = base + excl;
    __syncthreads();
    for (int i = t; i < m; i += 256) {
        unsigned v2 = stage[base + i];
        int pos = atomicAdd(&cnt[(v2 >> 19) & 255], 1);
        dstc_csr[pos] = (int)(v2 & 0x1FFFF) | (int)(((v2 >> 17) & 3) << 24);
    }
}

// ---------------- fused per-node sim via MFMA --------------------------------
// One wave per node. Per 16-edge batch: A = 16 gathered dst rows
// (lane(c16,g) loads hnf[dst[c16]][s*32+g*8], 4 VMEM/lane), B = src row
// broadcast to all cols -> D[r][c] = sim[r] for every c. Lane(c16,g) gets
// sims of edges g*4+j in acc[j]. Writer lane for edge ebase+c16 is
// (g==c16>>2, c16): it also loaded that edge's dstc. Rescale pass re-reads
// only this thread's own raw-w stores, packs dst|q15 for prop.
__global__ void node_sim_kernel(const _Float16* __restrict__ hnf,
    const int* __restrict__ row_ptr, const int* __restrict__ dstc_csr,
    const float* __restrict__ ew0, const float* __restrict__ ew1,
    const float* __restrict__ ew2, float2* __restrict__ wd_csr,
    unsigned* __restrict__ wq_csr, int N)
{
    const int gtid = blockIdx.x * blockDim.x + threadIdx.x;
    const int lane = threadIdx.x & 63;
    const int c16  = lane & 15;
    const int g    = lane >> 4;
    const int wv   = gtid >> 6;
    const int nwv  = (gridDim.x * blockDim.x) >> 6;
    const float sg0 = 1.f / (1.f + expf(-ew0[0]));
    const float sg1 = 1.f / (1.f + expf(-ew1[0]));
    const float sg2 = 1.f / (1.f + expf(-ew2[0]));
    const bool writer = ((c16 >> 2) == g);

    for (int n = wv; n < N; n += nwv) {
        const int beg = row_ptr[n], end = row_ptr[n + 1];
        const int deg = end - beg;
        if (deg == 0) continue;

        // B frags: src row slice (c16-independent broadcast)
        f16x8 bf[4];
#pragma unroll
        for (int s = 0; s < 4; ++s)
            bf[s] = *(const f16x8*)&hnf[(size_t)n * 128 + s * 32 + g * 8];

        float total = 0.f;
        const int nb = (deg + 15) >> 4;
        for (int kb = 0; kb < nb; ++kb) {
            const int ebase = beg + (kb << 4);
            const int rem = end - ebase;          // edges in this batch (1..16+)
            // per-lane dstc for edge ebase+c16
            int vv = (c16 < rem) ? dstc_csr[ebase + c16] : 0;
            int dl = (c16 < rem) ? (vv & 0x1FFFF) : n;
            // A frags: gathered dst rows
            f16x8 af[4];
#pragma unroll
            for (int s = 0; s < 4; ++s)
                af[s] = *(const f16x8*)&hnf[(size_t)dl * 128 + s * 32 + g * 8];

            f32x4 acc = {0.f, 0.f, 0.f, 0.f};
#pragma unroll
            for (int s = 0; s < 4; ++s)
                acc = __builtin_amdgcn_mfma_f32_16x16x32_f16(af[s], bf[s], acc, 0, 0, 0);

            // w for edges g*4+j
            float w[4];
#pragma unroll
            for (int j = 0; j < 4; ++j) {
                int ej = (g << 2) + j;
                int vj = __shfl(vv, ej);          // dstc of edge ebase+ej
                int cls = (vj >> 24) & 3;
                float sgc = (cls == 0) ? sg0 : (cls == 1) ? sg1 : sg2;
                float wj = sgc * acc[j];
                w[j] = (ej < rem) ? wj : 0.f;
                total += w[j];
            }
            // store raw (w, dstc) — writer lane owns edge ebase+c16
            if (writer && c16 < rem) {
                int j4 = c16 & 3;
                float wsel = (j4 == 0) ? w[0] : (j4 == 1) ? w[1]
                           : (j4 == 2) ? w[2] : w[3];
                float2 wd; wd.x = wsel; wd.y = __int_as_float(vv);
                wd_csr[ebase + c16] = wd;
            }
        }
        // total currently summed per-lane over its g's edges (replicated c16)
        total += __shfl_xor(total, 16);
        total += __shfl_xor(total, 32);
        float s = ALPHA_ * ((total > 0.f) ? 1.f / total : 1.f);

        // rescale + pack: each writer lane re-reads ITS OWN stores
        if (writer) {
            for (int e = beg + c16; e < end; e += 16) {
                float2 wd = wd_csr[e];
                float wp = wd.x * s;                     // in [0, 0.5]
                int q = (int)(wp * 65534.f + 0.5f);
                q = min(max(q, 0), 32767);
                wq_csr[e] = ((unsigned)__float_as_int(wd.y) & 0x1FFFFu)
                          | ((unsigned)q << 17);
            }
        }
    }
}

// ---------------- init f32 -> f16 -------------------------------------------
__global__ void cvt_kernel(const float* __restrict__ init,
                           _Float16* __restrict__ outh, int M4)
{
    int i = blockIdx.x * blockDim.x + threadIdx.x;
    int stride = gridDim.x * blockDim.x;
    for (; i < M4; i += stride) {
        float4 v = ((const float4*)init)[i];
        h4 o;
        o[0] = (_Float16)v.x; o[1] = (_Float16)v.y;
        o[2] = (_Float16)v.z; o[3] = (_Float16)v.w;
        ((h4*)outh)[i] = o;
    }
}

// ---------------- propagation: out = sum(w'*cur[dst]) + 0.5*init ------------
// One wave per node, 8 edge-subgroups x 8 lanes; 4B packed edge (dst|q15).
template<bool LAST>
__global__ void prop_kernel(const int* __restrict__ row_ptr,
    const unsigned* __restrict__ wq_csr,
    const _Float16* __restrict__ cur, const _Float16* __restrict__ inith,
    float* __restrict__ out32, _Float16* __restrict__ out16, int N)
{
    const int gtid = blockIdx.x * blockDim.x + threadIdx.x;
    const int lane = threadIdx.x & 63;
    const int sg   = lane >> 3;
    const int c8   = lane & 7;
    const int wv   = gtid >> 6;
    const int nwv  = (gridDim.x * blockDim.x) >> 6;
    const float dq = 1.f / 65534.f;
    for (int n = wv; n < N; n += nwv) {
        int beg = row_ptr[n], end = row_ptr[n + 1];
        float ax = 0.f, ay = 0.f;
#pragma unroll 4
        for (int e = beg + sg; e < end; e += 8) {
            unsigned u = wq_csr[e];
            int d = (int)(u & 0x1FFFFu);
            float w = (float)(u >> 17) * dq;
            h2 cv = *(const h2*)&cur[(size_t)d * 16 + c8 * 2];
            ax += w * (float)cv[0];
            ay += w * (float)cv[1];
        }
#pragma unroll
        for (int m = 8; m <= 32; m <<= 1) {
            ax += __shfl_xor(ax, m);
            ay += __shfl_xor(ay, m);
        }
        if (sg == 0) {
            h2 iv = *(const h2*)&inith[(size_t)n * 16 + c8 * 2];
            float r0 = ax + (1.f - ALPHA_) * (float)iv[0];
            float r1 = ay + (1.f - ALPHA_) * (float)iv[1];
            if (LAST) {
                float2 st; st.x = r0; st.y = r1;
                *(float2*)&out32[(size_t)n * 16 + c8 * 2] = st;
            } else {
                h2 st; st[0] = (_Float16)r0; st[1] = (_Float16)r1;
                *(h2*)&out16[(size_t)n * 16 + c8 * 2] = st;
            }
        }
    }
}

extern "C" void kernel_launch(void* const* d_in, const int* in_sizes, int n_in,
                              void* d_out, int out_size, void* d_ws, size_t ws_size,
                              hipStream_t stream)
{
    const float* feat  = (const float*)d_in[0];
    const float* initl = (const float*)d_in[1];
    const float* W     = (const float*)d_in[2];
    const float* b     = (const float*)d_in[3];
    const float* gam   = (const float*)d_in[4];
    const float* bet   = (const float*)d_in[5];
    const float* ew0   = (const float*)d_in[6];
    const float* ew1   = (const float*)d_in[7];
    const float* ew2   = (const float*)d_in[8];
    const int* s0  = (const int*)d_in[9];
    const int* dd0 = (const int*)d_in[10];
    const int* s1  = (const int*)d_in[11];
    const int* dd1 = (const int*)d_in[12];
    const int* s2  = (const int*)d_in[13];
    const int* dd2 = (const int*)d_in[14];

    const int N = in_sizes[0] / DD;
    const int E = in_sizes[9];
    const int totE = 3 * E;
    const int NB = (N + 255) >> 8;
    float* out = (float*)d_out;

    char* ws = (char*)d_ws;
    size_t off = 0;
    auto alloc = [&](size_t bytes) -> void* {
        void* p = ws + off;
        off += (bytes + 255) & ~(size_t)255;
        return p;
    };
    _Float16* hnf     = (_Float16*)alloc((size_t)N * DD * 2);
    int*      gcnt    = (int*)alloc((size_t)(NB + 1) * 4);
    int*      bbase   = (int*)alloc((size_t)(NB + 1) * 4);
    int*      gcur    = (int*)alloc((size_t)(NB + 1) * 4);
    int*      row_ptr = (int*)alloc((size_t)(N + 1) * 4);
    unsigned* stage   = (unsigned*)alloc((size_t)totE * 4);
    int*      dstc_csr= (int*)alloc((size_t)totE * 4);
    float2*   wd_csr  = (float2*)alloc((size_t)totE * 8);
    unsigned* wq_csr  = (unsigned*)alloc((size_t)totE * 4);
    _Float16* inith   = (_Float16*)alloc((size_t)N * CC * 2);
    _Float16* curA    = (_Float16*)alloc((size_t)N * CC * 2);
    _Float16* curB    = (_Float16*)alloc((size_t)N * CC * 2);

    // 1) feature transform (MFMA) -> f16 normalized rows
    ft_mfma_kernel<<<512, 256, 0, stream>>>(feat, W, b, gam, bet, hnf, N);

    // 2) CSR build: bucket count -> scan -> partition -> per-bucket finalize
    hipMemsetAsync(gcnt, 0, (size_t)NB * 4, stream);
    bcount_kernel<<<NB, 256, 0, stream>>>(s0, s1, s2, gcnt, E, NB);
    bscan_kernel<<<1, 256, 0, stream>>>(gcnt, bbase, gcur, NB, totE);
    bpart_kernel<<<NB, 256, 0, stream>>>(s0, dd0, s1, dd1, s2, dd2,
                                         gcur, stage, E, NB);
    csrfin_kernel<<<NB, 256, 0, stream>>>(stage, bbase, row_ptr, dstc_csr, N, totE);

    // 3) fused edge weights (MFMA sims) + per-node normalize -> packed 4B
    const int wblk = (N * 64 + 255) / 256;
    node_sim_kernel<<<wblk, 256, 0, stream>>>(hnf, row_ptr, dstc_csr,
                                              ew0, ew1, ew2, wd_csr, wq_csr, N);

    // 4) init -> f16, then 5 propagation layers (ping-pong, race-free)
    cvt_kernel<<<256, 256, 0, stream>>>(initl, inith, N * CC / 4);
    const _Float16* cs = inith;
    _Float16* bufs[2] = { curA, curB };
    for (int layer = 0; layer < 4; ++layer) {
        _Float16* dst = bufs[layer & 1];
        prop_kernel<false><<<wblk, 256, 0, stream>>>(row_ptr, wq_csr,
                                                     cs, inith, nullptr, dst, N);
        cs = dst;
    }
    prop_kernel<true><<<wblk, 256, 0, stream>>>(row_ptr, wq_csr,
                                                cs, inith, out, nullptr, N);
}

// Round 10
// 457.230 us; speedup vs baseline: 9.0584x; 1.0483x over previous
//
#include <hip/hip_runtime.h>
#include <hip/hip_fp8.h>
#include <math.h>

#define DD 128
#define CC 16
#define ALPHA_ 0.5f
#define EPS_LN 1e-5f
#define EPS_COS 1e-8f

typedef _Float16 h2 __attribute__((ext_vector_type(2)));
typedef _Float16 h4 __attribute__((ext_vector_type(4)));
typedef _Float16 f16x8 __attribute__((ext_vector_type(8)));
typedef float f32x4 __attribute__((ext_vector_type(4)));

__device__ __forceinline__ unsigned pk_fp8x4(float v0, float v1, float v2, float v3) {
#if __has_builtin(__builtin_amdgcn_cvt_pk_fp8_f32)
    int u = 0;
    u = __builtin_amdgcn_cvt_pk_fp8_f32(v0, v1, u, false);
    u = __builtin_amdgcn_cvt_pk_fp8_f32(v2, v3, u, true);
    return (unsigned)u;
#else
    __hip_fp8_e4m3 a(v0), b(v1), c(v2), d(v3);
    return (unsigned)a.__x | ((unsigned)b.__x << 8)
         | ((unsigned)c.__x << 16) | ((unsigned)d.__x << 24);
#endif
}

// ---------------- Kernel A: feature transform via MFMA -> fp8 rows ----------
// h^T: D[j][i] = sum_k W[j][k]*feat[i][k], mfma_f32_16x16x32_f16
// (layout verified on-chip in rounds 8/9). Output: L2-normalized rows in
// fp8 e4m3, 128 B/row (only consumer is node_sim's cosine dot).
__global__ __launch_bounds__(256, 2) void ft_mfma_kernel(
    const float* __restrict__ feat, const float* __restrict__ W,
    const float* __restrict__ bias, const float* __restrict__ gamma,
    const float* __restrict__ beta, unsigned* __restrict__ hn8, int N)
{
    const int lane = threadIdx.x & 63;
    const int c16  = lane & 15;
    const int g    = lane >> 4;
    const int wv   = (blockIdx.x * (int)blockDim.x + (int)threadIdx.x) >> 6;
    const int nwv  = ((int)gridDim.x * (int)blockDim.x) >> 6;

    f16x8 wf[8][4];
#pragma unroll
    for (int jt = 0; jt < 8; ++jt) {
        const float* wr = W + (size_t)(jt * 16 + c16) * 128 + g * 8;
#pragma unroll
        for (int s = 0; s < 4; ++s) {
            float4 lo = *(const float4*)(wr + s * 32);
            float4 hi = *(const float4*)(wr + s * 32 + 4);
            f16x8 f;
            f[0] = (_Float16)lo.x; f[1] = (_Float16)lo.y;
            f[2] = (_Float16)lo.z; f[3] = (_Float16)lo.w;
            f[4] = (_Float16)hi.x; f[5] = (_Float16)hi.y;
            f[6] = (_Float16)hi.z; f[7] = (_Float16)hi.w;
            wf[jt][s] = f;
        }
    }

    const int ntiles = (N + 15) >> 4;
    for (int t = wv; t < ntiles; t += nwv) {
        const int i = (t << 4) + c16;
        const float* fr = feat + (size_t)min(i, N - 1) * 128 + g * 8;
        f16x8 bf[4];
#pragma unroll
        for (int s = 0; s < 4; ++s) {
            float4 lo = *(const float4*)(fr + s * 32);
            float4 hi = *(const float4*)(fr + s * 32 + 4);
            f16x8 f;
            f[0] = (_Float16)lo.x; f[1] = (_Float16)lo.y;
            f[2] = (_Float16)lo.z; f[3] = (_Float16)lo.w;
            f[4] = (_Float16)hi.x; f[5] = (_Float16)hi.y;
            f[6] = (_Float16)hi.z; f[7] = (_Float16)hi.w;
            bf[s] = f;
        }

        f32x4 acc[8] = {};
#pragma unroll
        for (int s = 0; s < 4; ++s)
#pragma unroll
            for (int jt = 0; jt < 8; ++jt)
                acc[jt] = __builtin_amdgcn_mfma_f32_16x16x32_f16(
                    wf[jt][s], bf[s], acc[jt], 0, 0, 0);

        float s1 = 0.f, s2 = 0.f;
#pragma unroll
        for (int jt = 0; jt < 8; ++jt) {
            float4 bb = ((const float4*)bias)[jt * 4 + g];
            float h0 = acc[jt][0] + bb.x, h1 = acc[jt][1] + bb.y;
            float h2_ = acc[jt][2] + bb.z, h3 = acc[jt][3] + bb.w;
            acc[jt][0] = h0; acc[jt][1] = h1; acc[jt][2] = h2_; acc[jt][3] = h3;
            s1 += h0 + h1 + h2_ + h3;
            s2 += h0 * h0 + h1 * h1 + h2_ * h2_ + h3 * h3;
        }
        s1 += __shfl_xor(s1, 16); s1 += __shfl_xor(s1, 32);
        s2 += __shfl_xor(s2, 16); s2 += __shfl_xor(s2, 32);
        float mu   = s1 * (1.f / 128.f);
        float var  = s2 * (1.f / 128.f) - mu * mu;
        float rstd = rsqrtf(var + EPS_LN);

        float nsq = 0.f;
#pragma unroll
        for (int jt = 0; jt < 8; ++jt) {
            float4 gg = ((const float4*)gamma)[jt * 4 + g];
            float4 be = ((const float4*)beta)[jt * 4 + g];
            float v0 = fmaxf((acc[jt][0] - mu) * rstd * gg.x + be.x, 0.f);
            float v1 = fmaxf((acc[jt][1] - mu) * rstd * gg.y + be.y, 0.f);
            float v2 = fmaxf((acc[jt][2] - mu) * rstd * gg.z + be.z, 0.f);
            float v3 = fmaxf((acc[jt][3] - mu) * rstd * gg.w + be.w, 0.f);
            acc[jt][0] = v0; acc[jt][1] = v1; acc[jt][2] = v2; acc[jt][3] = v3;
            nsq += v0 * v0 + v1 * v1 + v2 * v2 + v3 * v3;
        }
        nsq += __shfl_xor(nsq, 16); nsq += __shfl_xor(nsq, 32);
        float inv = 1.f / fmaxf(sqrtf(nsq), EPS_COS);

        if (i < N) {
#pragma unroll
            for (int jt = 0; jt < 8; ++jt) {
                hn8[(size_t)i * 32 + jt * 4 + g] =
                    pk_fp8x4(acc[jt][0] * inv, acc[jt][1] * inv,
                             acc[jt][2] * inv, acc[jt][3] * inv);
            }
        }
    }
}

// ================= CSR build: 2-level bucket sort ===========================
__global__ void bcount_kernel(const int* __restrict__ s0, const int* __restrict__ s1,
                              const int* __restrict__ s2, int* __restrict__ gcnt,
                              int E, int NB)
{
    __shared__ int cnt[512];
    const int tid = threadIdx.x;
    for (int i = tid; i < NB; i += 256) cnt[i] = 0;
    __syncthreads();
    const int tot = 3 * E;
    const int chunk = (tot + gridDim.x - 1) / gridDim.x;
    const int lo = blockIdx.x * chunk, hi = min(lo + chunk, tot);
    for (int i = lo + tid; i < hi; i += 256) {
        int src = (i < E) ? s0[i] : (i < 2 * E) ? s1[i - E] : s2[i - 2 * E];
        atomicAdd(&cnt[src >> 8], 1);
    }
    __syncthreads();
    for (int i = tid; i < NB; i += 256)
        if (cnt[i]) atomicAdd(&gcnt[i], cnt[i]);
}

__global__ void bscan_kernel(const int* __restrict__ gcnt, int* __restrict__ bbase,
                             int* __restrict__ gcur, int NB, int totE)
{
    __shared__ int wsum[4];
    const int t = threadIdx.x;
    const int lane = t & 63;
    int a0 = (2 * t     < NB) ? gcnt[2 * t]     : 0;
    int a1 = (2 * t + 1 < NB) ? gcnt[2 * t + 1] : 0;
    int ts = a0 + a1;
    int v = ts;
#pragma unroll
    for (int m = 1; m <= 32; m <<= 1) {
        int u = __shfl_up(v, m);
        if (lane >= m) v += u;
    }
    if (lane == 63) wsum[t >> 6] = v;
    __syncthreads();
    int woff = 0;
    for (int w = 0; w < (t >> 6); ++w) woff += wsum[w];
    int excl = woff + v - ts;
    if (2 * t < NB)     { bbase[2 * t]     = excl;      gcur[2 * t]     = excl; }
    if (2 * t + 1 < NB) { bbase[2 * t + 1] = excl + a0; gcur[2 * t + 1] = excl + a0; }
    if (t == 0) bbase[NB] = totE;
}

__global__ void bpart_kernel(
    const int* __restrict__ s0, const int* __restrict__ d0,
    const int* __restrict__ s1, const int* __restrict__ d1,
    const int* __restrict__ s2, const int* __restrict__ d2,
    int* __restrict__ gcur, unsigned* __restrict__ stage, int E, int NB)
{
    __shared__ int cnt[512];
    __shared__ int rbase[512];
    const int tid = threadIdx.x;
    for (int i = tid; i < NB; i += 256) cnt[i] = 0;
    __syncthreads();
    const int tot = 3 * E;
    const int chunk = (tot + gridDim.x - 1) / gridDim.x;
    const int lo = blockIdx.x * chunk, hi = min(lo + chunk, tot);
    for (int i = lo + tid; i < hi; i += 256) {
        int src = (i < E) ? s0[i] : (i < 2 * E) ? s1[i - E] : s2[i - 2 * E];
        atomicAdd(&cnt[src >> 8], 1);
    }
    __syncthreads();
    for (int i = tid; i < NB; i += 256) {
        int c = cnt[i];
        rbase[i] = c ? atomicAdd(&gcur[i], c) : 0;
        cnt[i] = 0;
    }
    __syncthreads();
    for (int i = lo + tid; i < hi; i += 256) {
        int src, dst, cls;
        if (i < E)          { src = s0[i];         dst = d0[i];         cls = 0; }
        else if (i < 2 * E) { src = s1[i - E];     dst = d1[i - E];     cls = 1; }
        else                { src = s2[i - 2 * E]; dst = d2[i - 2 * E]; cls = 2; }
        int b = src >> 8;
        int pos = rbase[b] + atomicAdd(&cnt[b], 1);
        stage[pos] = (unsigned)dst | ((unsigned)cls << 17) | ((unsigned)(src & 255) << 19);
    }
}

__global__ void csrfin_kernel(const unsigned* __restrict__ stage,
                              const int* __restrict__ bbase,
                              int* __restrict__ row_ptr, int* __restrict__ dstc_csr,
                              int N, int totE)
{
    __shared__ int cnt[256];
    __shared__ int wsum[4];
    const int b = blockIdx.x;
    const int t = threadIdx.x;
    const int lane = t & 63;
    const int lo = b << 8;
    const int base = bbase[b];
    const int m = bbase[b + 1] - base;

    cnt[t] = 0;
    __syncthreads();
    for (int i = t; i < m; i += 256)
        atomicAdd(&cnt[(stage[base + i] >> 19) & 255], 1);
    __syncthreads();
    int c = cnt[t];
    int v = c;
#pragma unroll
    for (int mm = 1; mm <= 32; mm <<= 1) {
        int u = __shfl_up(v, mm);
        if (lane >= mm) v += u;
    }
    if (lane == 63) wsum[t >> 6] = v;
    __syncthreads();
    int woff = 0;
    for (int w = 0; w < (t >> 6); ++w) woff += wsum[w];
    int excl = woff + v - c;
    if (lo + t < N) row_ptr[lo + t] = base + excl;
    if (b == 0 && t == 0) row_ptr[N] = totE;
    __syncthreads();
    cnt[t] = base + excl;
    __syncthreads();
    for (int i = t; i < m; i += 256) {
        unsigned v2 = stage[base + i];
        int pos = atomicAdd(&cnt[(v2 >> 19) & 255], 1);
        dstc_csr[pos] = (int)(v2 & 0x1FFFF) | (int)(((v2 >> 17) & 3) << 24);
    }
}

// ---------------- fused per-node sim via fp8 MFMA ---------------------------
// One wave per node. 16-edge batches: A = gathered dst fp8 rows (4x8B/lane),
// B = src row broadcast. D[r][c]=sim[r]. Writer lane packs the edge word
// directly: dst(17b) | biased-q15(raw w). Normalization lives in scl[n].
__global__ void node_sim_kernel(const unsigned char* __restrict__ hn8,
    const int* __restrict__ row_ptr, const int* __restrict__ dstc_csr,
    const float* __restrict__ ew0, const float* __restrict__ ew1,
    const float* __restrict__ ew2, unsigned* __restrict__ wq_csr,
    float* __restrict__ scl, int N)
{
    const int gtid = blockIdx.x * blockDim.x + threadIdx.x;
    const int lane = threadIdx.x & 63;
    const int c16  = lane & 15;
    const int g    = lane >> 4;
    const int wv   = gtid >> 6;
    const int nwv  = (gridDim.x * blockDim.x) >> 6;
    const float sg0 = 1.f / (1.f + expf(-ew0[0]));
    const float sg1 = 1.f / (1.f + expf(-ew1[0]));
    const float sg2 = 1.f / (1.f + expf(-ew2[0]));
    const bool writer = ((c16 >> 2) == g);

    for (int n = wv; n < N; n += nwv) {
        const int beg = row_ptr[n], end = row_ptr[n + 1];
        const int deg = end - beg;
        if (deg == 0) { if (lane == 0) scl[n] = ALPHA_; continue; }

        // B frags: src row slice (c16-independent broadcast), 8 fp8 = i64
        long bf[4];
#pragma unroll
        for (int s = 0; s < 4; ++s)
            bf[s] = *(const long*)(hn8 + (size_t)n * 128 + s * 32 + g * 8);

        float total = 0.f;
        const int nb = (deg + 15) >> 4;
        for (int kb = 0; kb < nb; ++kb) {
            const int ebase = beg + (kb << 4);
            const int rem = end - ebase;
            int vv = (c16 < rem) ? dstc_csr[ebase + c16] : 0;
            int dl = (c16 < rem) ? (vv & 0x1FFFF) : n;
            const unsigned char* rp = hn8 + (size_t)dl * 128 + g * 8;
            long af[4];
#pragma unroll
            for (int s = 0; s < 4; ++s)
                af[s] = *(const long*)(rp + s * 32);

            f32x4 acc = {0.f, 0.f, 0.f, 0.f};
#pragma unroll
            for (int s = 0; s < 4; ++s)
                acc = __builtin_amdgcn_mfma_f32_16x16x32_fp8_fp8(
                    af[s], bf[s], acc, 0, 0, 0);

            float w4[4];
#pragma unroll
            for (int j = 0; j < 4; ++j) {
                int ej = (g << 2) + j;
                int vj = __shfl(vv, ej);
                int cls = (vj >> 24) & 3;
                float sgc = (cls == 0) ? sg0 : (cls == 1) ? sg1 : sg2;
                float wj = sgc * acc[j];
                w4[j] = wj;
                if (ej < rem) total += wj;
            }
            if (writer && c16 < rem) {
                int j4 = c16 & 3;
                float ws = (j4 == 0) ? w4[0] : (j4 == 1) ? w4[1]
                         : (j4 == 2) ? w4[2] : w4[3];
                int q = (int)(ws * 16000.f + ((ws >= 0.f) ? 0.5f : -0.5f)) + 16384;
                q = min(max(q, 0), 32767);
                wq_csr[ebase + c16] = ((unsigned)vv & 0x1FFFFu)
                                    | ((unsigned)q << 17);
            }
        }
        total += __shfl_xor(total, 16);
        total += __shfl_xor(total, 32);
        if (lane == 0)
            scl[n] = ALPHA_ * ((total > 0.f) ? 1.f / total : 1.f);
    }
}

// ---------------- init f32 -> f16 -------------------------------------------
__global__ void cvt_kernel(const float* __restrict__ init,
                           _Float16* __restrict__ outh, int M4)
{
    int i = blockIdx.x * blockDim.x + threadIdx.x;
    int stride = gridDim.x * blockDim.x;
    for (; i < M4; i += stride) {
        float4 v = ((const float4*)init)[i];
        h4 o;
        o[0] = (_Float16)v.x; o[1] = (_Float16)v.y;
        o[2] = (_Float16)v.z; o[3] = (_Float16)v.w;
        ((h4*)outh)[i] = o;
    }
}

// ---------------- propagation: out = scl*sum(wraw*cur[dst]) + 0.5*init ------
// One wave per node, 8 edge-subgroups x 8 lanes; 4B packed edge (dst|q15raw).
template<bool LAST>
__global__ void prop_kernel(const int* __restrict__ row_ptr,
    const unsigned* __restrict__ wq_csr, const float* __restrict__ scl,
    const _Float16* __restrict__ cur, const _Float16* __restrict__ inith,
    float* __restrict__ out32, _Float16* __restrict__ out16, int N)
{
    const int gtid = blockIdx.x * blockDim.x + threadIdx.x;
    const int lane = threadIdx.x & 63;
    const int sg   = lane >> 3;
    const int c8   = lane & 7;
    const int wv   = gtid >> 6;
    const int nwv  = (gridDim.x * blockDim.x) >> 6;
    const float dq = 1.f / 16000.f;
    for (int n = wv; n < N; n += nwv) {
        int beg = row_ptr[n], end = row_ptr[n + 1];
        float ax = 0.f, ay = 0.f;
#pragma unroll 4
        for (int e = beg + sg; e < end; e += 8) {
            unsigned u = wq_csr[e];
            int d = (int)(u & 0x1FFFFu);
            float w = (float)((int)(u >> 17) - 16384) * dq;
            h2 cv = *(const h2*)&cur[(size_t)d * 16 + c8 * 2];
            ax += w * (float)cv[0];
            ay += w * (float)cv[1];
        }
#pragma unroll
        for (int m = 8; m <= 32; m <<= 1) {
            ax += __shfl_xor(ax, m);
            ay += __shfl_xor(ay, m);
        }
        if (sg == 0) {
            float sc = scl[n];
            h2 iv = *(const h2*)&inith[(size_t)n * 16 + c8 * 2];
            float r0 = sc * ax + (1.f - ALPHA_) * (float)iv[0];
            float r1 = sc * ay + (1.f - ALPHA_) * (float)iv[1];
            if (LAST) {
                float2 st; st.x = r0; st.y = r1;
                *(float2*)&out32[(size_t)n * 16 + c8 * 2] = st;
            } else {
                h2 st; st[0] = (_Float16)r0; st[1] = (_Float16)r1;
                *(h2*)&out16[(size_t)n * 16 + c8 * 2] = st;
            }
        }
    }
}

extern "C" void kernel_launch(void* const* d_in, const int* in_sizes, int n_in,
                              void* d_out, int out_size, void* d_ws, size_t ws_size,
                              hipStream_t stream)
{
    const float* feat  = (const float*)d_in[0];
    const float* initl = (const float*)d_in[1];
    const float* W     = (const float*)d_in[2];
    const float* b     = (const float*)d_in[3];
    const float* gam   = (const float*)d_in[4];
    const float* bet   = (const float*)d_in[5];
    const float* ew0   = (const float*)d_in[6];
    const float* ew1   = (const float*)d_in[7];
    const float* ew2   = (const float*)d_in[8];
    const int* s0  = (const int*)d_in[9];
    const int* dd0 = (const int*)d_in[10];
    const int* s1  = (const int*)d_in[11];
    const int* dd1 = (const int*)d_in[12];
    const int* s2  = (const int*)d_in[13];
    const int* dd2 = (const int*)d_in[14];

    const int N = in_sizes[0] / DD;
    const int E = in_sizes[9];
    const int totE = 3 * E;
    const int NB = (N + 255) >> 8;
    float* out = (float*)d_out;

    char* ws = (char*)d_ws;
    size_t off = 0;
    auto alloc = [&](size_t bytes) -> void* {
        void* p = ws + off;
        off += (bytes + 255) & ~(size_t)255;
        return p;
    };
    unsigned*  hn8     = (unsigned*)alloc((size_t)N * DD);          // fp8 rows
    int*       gcnt    = (int*)alloc((size_t)(NB + 1) * 4);
    int*       bbase   = (int*)alloc((size_t)(NB + 1) * 4);
    int*       gcur    = (int*)alloc((size_t)(NB + 1) * 4);
    int*       row_ptr = (int*)alloc((size_t)(N + 1) * 4);
    unsigned*  stage   = (unsigned*)alloc((size_t)totE * 4);
    int*       dstc_csr= (int*)alloc((size_t)totE * 4);
    unsigned*  wq_csr  = (unsigned*)alloc((size_t)totE * 4);
    float*     scl     = (float*)alloc((size_t)N * 4);
    _Float16*  inith   = (_Float16*)alloc((size_t)N * CC * 2);
    _Float16*  curA    = (_Float16*)alloc((size_t)N * CC * 2);
    _Float16*  curB    = (_Float16*)alloc((size_t)N * CC * 2);

    // 1) feature transform (MFMA) -> fp8 normalized rows
    ft_mfma_kernel<<<512, 256, 0, stream>>>(feat, W, b, gam, bet, hn8, N);

    // 2) CSR build: bucket count -> scan -> partition -> per-bucket finalize
    hipMemsetAsync(gcnt, 0, (size_t)NB * 4, stream);
    bcount_kernel<<<NB, 256, 0, stream>>>(s0, s1, s2, gcnt, E, NB);
    bscan_kernel<<<1, 256, 0, stream>>>(gcnt, bbase, gcur, NB, totE);
    bpart_kernel<<<NB, 256, 0, stream>>>(s0, dd0, s1, dd1, s2, dd2,
                                         gcur, stage, E, NB);
    csrfin_kernel<<<NB, 256, 0, stream>>>(stage, bbase, row_ptr, dstc_csr, N, totE);

    // 3) fused edge weights (fp8 MFMA sims) -> packed 4B edges + scl
    const int wblk = (N * 64 + 255) / 256;
    node_sim_kernel<<<wblk, 256, 0, stream>>>((const unsigned char*)hn8,
                                              row_ptr, dstc_csr,
                                              ew0, ew1, ew2, wq_csr, scl, N);

    // 4) init -> f16, then 5 propagation layers (ping-pong, race-free)
    cvt_kernel<<<256, 256, 0, stream>>>(initl, inith, N * CC / 4);
    const _Float16* cs = inith;
    _Float16* bufs[2] = { curA, curB };
    for (int layer = 0; layer < 4; ++layer) {
        _Float16* dst = bufs[layer & 1];
        prop_kernel<false><<<wblk, 256, 0, stream>>>(row_ptr, wq_csr, scl,
                                                     cs, inith, nullptr, dst, N);
        cs = dst;
    }
    prop_kernel<true><<<wblk, 256, 0, stream>>>(row_ptr, wq_csr, scl,
                                                cs, inith, out, nullptr, N);
}

// Round 11
// 385.958 us; speedup vs baseline: 10.7311x; 1.1847x over previous
//
#include <hip/hip_runtime.h>
#include <hip/hip_fp8.h>
#include <math.h>

#define DD 128
#define CC 16
#define ALPHA_ 0.5f
#define EPS_LN 1e-5f
#define EPS_COS 1e-8f

typedef _Float16 h2 __attribute__((ext_vector_type(2)));
typedef _Float16 h4 __attribute__((ext_vector_type(4)));
typedef _Float16 f16x8 __attribute__((ext_vector_type(8)));
typedef float f32x4 __attribute__((ext_vector_type(4)));
typedef long lx2 __attribute__((ext_vector_type(2)));

__device__ __forceinline__ unsigned pk_fp8x4(float v0, float v1, float v2, float v3) {
#if __has_builtin(__builtin_amdgcn_cvt_pk_fp8_f32)
    int u = 0;
    u = __builtin_amdgcn_cvt_pk_fp8_f32(v0, v1, u, false);
    u = __builtin_amdgcn_cvt_pk_fp8_f32(v2, v3, u, true);
    return (unsigned)u;
#else
    __hip_fp8_e4m3 a(v0), b(v1), c(v2), d(v3);
    return (unsigned)a.__x | ((unsigned)b.__x << 8)
         | ((unsigned)c.__x << 16) | ((unsigned)d.__x << 24);
#endif
}

// ---------------- Kernel A: feature transform via MFMA -> fp8 rows ----------
__global__ __launch_bounds__(256, 2) void ft_mfma_kernel(
    const float* __restrict__ feat, const float* __restrict__ W,
    const float* __restrict__ bias, const float* __restrict__ gamma,
    const float* __restrict__ beta, unsigned* __restrict__ hn8, int N)
{
    const int lane = threadIdx.x & 63;
    const int c16  = lane & 15;
    const int g    = lane >> 4;
    const int wv   = (blockIdx.x * (int)blockDim.x + (int)threadIdx.x) >> 6;
    const int nwv  = ((int)gridDim.x * (int)blockDim.x) >> 6;

    f16x8 wf[8][4];
#pragma unroll
    for (int jt = 0; jt < 8; ++jt) {
        const float* wr = W + (size_t)(jt * 16 + c16) * 128 + g * 8;
#pragma unroll
        for (int s = 0; s < 4; ++s) {
            float4 lo = *(const float4*)(wr + s * 32);
            float4 hi = *(const float4*)(wr + s * 32 + 4);
            f16x8 f;
            f[0] = (_Float16)lo.x; f[1] = (_Float16)lo.y;
            f[2] = (_Float16)lo.z; f[3] = (_Float16)lo.w;
            f[4] = (_Float16)hi.x; f[5] = (_Float16)hi.y;
            f[6] = (_Float16)hi.z; f[7] = (_Float16)hi.w;
            wf[jt][s] = f;
        }
    }

    const int ntiles = (N + 15) >> 4;
    for (int t = wv; t < ntiles; t += nwv) {
        const int i = (t << 4) + c16;
        const float* fr = feat + (size_t)min(i, N - 1) * 128 + g * 8;
        f16x8 bf[4];
#pragma unroll
        for (int s = 0; s < 4; ++s) {
            float4 lo = *(const float4*)(fr + s * 32);
            float4 hi = *(const float4*)(fr + s * 32 + 4);
            f16x8 f;
            f[0] = (_Float16)lo.x; f[1] = (_Float16)lo.y;
            f[2] = (_Float16)lo.z; f[3] = (_Float16)lo.w;
            f[4] = (_Float16)hi.x; f[5] = (_Float16)hi.y;
            f[6] = (_Float16)hi.z; f[7] = (_Float16)hi.w;
            bf[s] = f;
        }

        f32x4 acc[8] = {};
#pragma unroll
        for (int s = 0; s < 4; ++s)
#pragma unroll
            for (int jt = 0; jt < 8; ++jt)
                acc[jt] = __builtin_amdgcn_mfma_f32_16x16x32_f16(
                    wf[jt][s], bf[s], acc[jt], 0, 0, 0);

        float s1 = 0.f, s2 = 0.f;
#pragma unroll
        for (int jt = 0; jt < 8; ++jt) {
            float4 bb = ((const float4*)bias)[jt * 4 + g];
            float h0 = acc[jt][0] + bb.x, h1 = acc[jt][1] + bb.y;
            float h2_ = acc[jt][2] + bb.z, h3 = acc[jt][3] + bb.w;
            acc[jt][0] = h0; acc[jt][1] = h1; acc[jt][2] = h2_; acc[jt][3] = h3;
            s1 += h0 + h1 + h2_ + h3;
            s2 += h0 * h0 + h1 * h1 + h2_ * h2_ + h3 * h3;
        }
        s1 += __shfl_xor(s1, 16); s1 += __shfl_xor(s1, 32);
        s2 += __shfl_xor(s2, 16); s2 += __shfl_xor(s2, 32);
        float mu   = s1 * (1.f / 128.f);
        float var  = s2 * (1.f / 128.f) - mu * mu;
        float rstd = rsqrtf(var + EPS_LN);

        float nsq = 0.f;
#pragma unroll
        for (int jt = 0; jt < 8; ++jt) {
            float4 gg = ((const float4*)gamma)[jt * 4 + g];
            float4 be = ((const float4*)beta)[jt * 4 + g];
            float v0 = fmaxf((acc[jt][0] - mu) * rstd * gg.x + be.x, 0.f);
            float v1 = fmaxf((acc[jt][1] - mu) * rstd * gg.y + be.y, 0.f);
            float v2 = fmaxf((acc[jt][2] - mu) * rstd * gg.z + be.z, 0.f);
            float v3 = fmaxf((acc[jt][3] - mu) * rstd * gg.w + be.w, 0.f);
            acc[jt][0] = v0; acc[jt][1] = v1; acc[jt][2] = v2; acc[jt][3] = v3;
            nsq += v0 * v0 + v1 * v1 + v2 * v2 + v3 * v3;
        }
        nsq += __shfl_xor(nsq, 16); nsq += __shfl_xor(nsq, 32);
        float inv = 1.f / fmaxf(sqrtf(nsq), EPS_COS);

        if (i < N) {
#pragma unroll
            for (int jt = 0; jt < 8; ++jt) {
                hn8[(size_t)i * 32 + jt * 4 + g] =
                    pk_fp8x4(acc[jt][0] * inv, acc[jt][1] * inv,
                             acc[jt][2] * inv, acc[jt][3] * inv);
            }
        }
    }
}

// ================= CSR build: 2-level bucket sort ===========================
__global__ void bcount_kernel(const int* __restrict__ s0, const int* __restrict__ s1,
                              const int* __restrict__ s2, int* __restrict__ gcnt,
                              int E, int NB)
{
    __shared__ int cnt[512];
    const int tid = threadIdx.x;
    for (int i = tid; i < NB; i += 256) cnt[i] = 0;
    __syncthreads();
    const int tot = 3 * E;
    const int chunk = (tot + gridDim.x - 1) / gridDim.x;
    const int lo = blockIdx.x * chunk, hi = min(lo + chunk, tot);
    for (int i = lo + tid; i < hi; i += 256) {
        int src = (i < E) ? s0[i] : (i < 2 * E) ? s1[i - E] : s2[i - 2 * E];
        atomicAdd(&cnt[src >> 8], 1);
    }
    __syncthreads();
    for (int i = tid; i < NB; i += 256)
        if (cnt[i]) atomicAdd(&gcnt[i], cnt[i]);
}

__global__ void bscan_kernel(const int* __restrict__ gcnt, int* __restrict__ bbase,
                             int* __restrict__ gcur, int NB, int totE)
{
    __shared__ int wsum[4];
    const int t = threadIdx.x;
    const int lane = t & 63;
    int a0 = (2 * t     < NB) ? gcnt[2 * t]     : 0;
    int a1 = (2 * t + 1 < NB) ? gcnt[2 * t + 1] : 0;
    int ts = a0 + a1;
    int v = ts;
#pragma unroll
    for (int m = 1; m <= 32; m <<= 1) {
        int u = __shfl_up(v, m);
        if (lane >= m) v += u;
    }
    if (lane == 63) wsum[t >> 6] = v;
    __syncthreads();
    int woff = 0;
    for (int w = 0; w < (t >> 6); ++w) woff += wsum[w];
    int excl = woff + v - ts;
    if (2 * t < NB)     { bbase[2 * t]     = excl;      gcur[2 * t]     = excl; }
    if (2 * t + 1 < NB) { bbase[2 * t + 1] = excl + a0; gcur[2 * t + 1] = excl + a0; }
    if (t == 0) bbase[NB] = totE;
}

__global__ void bpart_kernel(
    const int* __restrict__ s0, const int* __restrict__ d0,
    const int* __restrict__ s1, const int* __restrict__ d1,
    const int* __restrict__ s2, const int* __restrict__ d2,
    int* __restrict__ gcur, unsigned* __restrict__ stage, int E, int NB)
{
    __shared__ int cnt[512];
    __shared__ int rbase[512];
    const int tid = threadIdx.x;
    for (int i = tid; i < NB; i += 256) cnt[i] = 0;
    __syncthreads();
    const int tot = 3 * E;
    const int chunk = (tot + gridDim.x - 1) / gridDim.x;
    const int lo = blockIdx.x * chunk, hi = min(lo + chunk, tot);
    for (int i = lo + tid; i < hi; i += 256) {
        int src = (i < E) ? s0[i] : (i < 2 * E) ? s1[i - E] : s2[i - 2 * E];
        atomicAdd(&cnt[src >> 8], 1);
    }
    __syncthreads();
    for (int i = tid; i < NB; i += 256) {
        int c = cnt[i];
        rbase[i] = c ? atomicAdd(&gcur[i], c) : 0;
        cnt[i] = 0;
    }
    __syncthreads();
    for (int i = lo + tid; i < hi; i += 256) {
        int src, dst, cls;
        if (i < E)          { src = s0[i];         dst = d0[i];         cls = 0; }
        else if (i < 2 * E) { src = s1[i - E];     dst = d1[i - E];     cls = 1; }
        else                { src = s2[i - 2 * E]; dst = d2[i - 2 * E]; cls = 2; }
        int b = src >> 8;
        int pos = rbase[b] + atomicAdd(&cnt[b], 1);
        stage[pos] = (unsigned)dst | ((unsigned)cls << 17) | ((unsigned)(src & 255) << 19);
    }
}

__global__ void csrfin_kernel(const unsigned* __restrict__ stage,
                              const int* __restrict__ bbase,
                              int* __restrict__ row_ptr, int* __restrict__ dstc_csr,
                              int N, int totE)
{
    __shared__ int cnt[256];
    __shared__ int wsum[4];
    const int b = blockIdx.x;
    const int t = threadIdx.x;
    const int lane = t & 63;
    const int lo = b << 8;
    const int base = bbase[b];
    const int m = bbase[b + 1] - base;

    cnt[t] = 0;
    __syncthreads();
    for (int i = t; i < m; i += 256)
        atomicAdd(&cnt[(stage[base + i] >> 19) & 255], 1);
    __syncthreads();
    int c = cnt[t];
    int v = c;
#pragma unroll
    for (int mm = 1; mm <= 32; mm <<= 1) {
        int u = __shfl_up(v, mm);
        if (lane >= mm) v += u;
    }
    if (lane == 63) wsum[t >> 6] = v;
    __syncthreads();
    int woff = 0;
    for (int w = 0; w < (t >> 6); ++w) woff += wsum[w];
    int excl = woff + v - c;
    if (lo + t < N) row_ptr[lo + t] = base + excl;
    if (b == 0 && t == 0) row_ptr[N] = totE;
    __syncthreads();
    cnt[t] = base + excl;
    __syncthreads();
    for (int i = t; i < m; i += 256) {
        unsigned v2 = stage[base + i];
        int pos = atomicAdd(&cnt[(v2 >> 19) & 255], 1);
        dstc_csr[pos] = (int)(v2 & 0x1FFFF) | (int)(((v2 >> 17) & 3) << 24);
    }
}

// ---------------- fused per-node sim via fp8 MFMA ---------------------------
// 16B row loads: the MFMA dot is invariant under any k-permutation applied
// identically to A and B frags; both use per-lane offsets {g*16, g*16+64},
// split into 8B halves as the 4 frags. Halves gather-instruction count.
__global__ void node_sim_kernel(const unsigned char* __restrict__ hn8,
    const int* __restrict__ row_ptr, const int* __restrict__ dstc_csr,
    const float* __restrict__ ew0, const float* __restrict__ ew1,
    const float* __restrict__ ew2, unsigned* __restrict__ wq_csr,
    float* __restrict__ scl, int N)
{
    const int gtid = blockIdx.x * blockDim.x + threadIdx.x;
    const int lane = threadIdx.x & 63;
    const int c16  = lane & 15;
    const int g    = lane >> 4;
    const int wv   = gtid >> 6;
    const int nwv  = (gridDim.x * blockDim.x) >> 6;
    const float sg0 = 1.f / (1.f + expf(-ew0[0]));
    const float sg1 = 1.f / (1.f + expf(-ew1[0]));
    const float sg2 = 1.f / (1.f + expf(-ew2[0]));
    const bool writer = ((c16 >> 2) == g);

    for (int n = wv; n < N; n += nwv) {
        const int beg = row_ptr[n], end = row_ptr[n + 1];
        const int deg = end - beg;
        if (deg == 0) { if (lane == 0) scl[n] = ALPHA_; continue; }

        const unsigned char* sp = hn8 + (size_t)n * 128 + g * 16;
        lx2 B0 = *(const lx2*)sp;
        lx2 B1 = *(const lx2*)(sp + 64);

        float total = 0.f;
        const int nb = (deg + 15) >> 4;
        for (int kb = 0; kb < nb; ++kb) {
            const int ebase = beg + (kb << 4);
            const int rem = end - ebase;
            int vv = (c16 < rem) ? dstc_csr[ebase + c16] : 0;
            int dl = (c16 < rem) ? (vv & 0x1FFFF) : n;
            const unsigned char* rp = hn8 + (size_t)dl * 128 + g * 16;
            lx2 A0 = *(const lx2*)rp;
            lx2 A1 = *(const lx2*)(rp + 64);

            f32x4 acc = {0.f, 0.f, 0.f, 0.f};
            acc = __builtin_amdgcn_mfma_f32_16x16x32_fp8_fp8(A0[0], B0[0], acc, 0, 0, 0);
            acc = __builtin_amdgcn_mfma_f32_16x16x32_fp8_fp8(A0[1], B0[1], acc, 0, 0, 0);
            acc = __builtin_amdgcn_mfma_f32_16x16x32_fp8_fp8(A1[0], B1[0], acc, 0, 0, 0);
            acc = __builtin_amdgcn_mfma_f32_16x16x32_fp8_fp8(A1[1], B1[1], acc, 0, 0, 0);

            float w4[4];
#pragma unroll
            for (int j = 0; j < 4; ++j) {
                int ej = (g << 2) + j;
                int vj = __shfl(vv, ej);
                int cls = (vj >> 24) & 3;
                float sgc = (cls == 0) ? sg0 : (cls == 1) ? sg1 : sg2;
                float wj = sgc * acc[j];
                w4[j] = wj;
                if (ej < rem) total += wj;
            }
            if (writer && c16 < rem) {
                int j4 = c16 & 3;
                float ws = (j4 == 0) ? w4[0] : (j4 == 1) ? w4[1]
                         : (j4 == 2) ? w4[2] : w4[3];
                int q = (int)(ws * 16000.f + ((ws >= 0.f) ? 0.5f : -0.5f)) + 16384;
                q = min(max(q, 0), 32767);
                wq_csr[ebase + c16] = ((unsigned)vv & 0x1FFFFu)
                                    | ((unsigned)q << 17);
            }
        }
        total += __shfl_xor(total, 16);
        total += __shfl_xor(total, 32);
        if (lane == 0)
            scl[n] = ALPHA_ * ((total > 0.f) ? 1.f / total : 1.f);
    }
}

// ---------------- init f32 -> f16 -------------------------------------------
__global__ void cvt_kernel(const float* __restrict__ init,
                           _Float16* __restrict__ outh, int M4)
{
    int i = blockIdx.x * blockDim.x + threadIdx.x;
    int stride = gridDim.x * blockDim.x;
    for (; i < M4; i += stride) {
        float4 v = ((const float4*)init)[i];
        h4 o;
        o[0] = (_Float16)v.x; o[1] = (_Float16)v.y;
        o[2] = (_Float16)v.z; o[3] = (_Float16)v.w;
        ((h4*)outh)[i] = o;
    }
}

// ---------------- propagation: out = scl*sum(wraw*cur[dst]) + 0.5*init ------
// One wave per node, 16 edge-subgroups x 4 lanes (h4/lane -> 16 edges in
// flight); 4B packed edge (dst|q15raw).
template<bool LAST>
__global__ void prop_kernel(const int* __restrict__ row_ptr,
    const unsigned* __restrict__ wq_csr, const float* __restrict__ scl,
    const _Float16* __restrict__ cur, const _Float16* __restrict__ inith,
    float* __restrict__ out32, _Float16* __restrict__ out16, int N)
{
    const int gtid = blockIdx.x * blockDim.x + threadIdx.x;
    const int lane = threadIdx.x & 63;
    const int sg   = lane >> 2;      // 16 subgroups
    const int c4   = lane & 3;       // classes c4*4 .. c4*4+3
    const int wv   = gtid >> 6;
    const int nwv  = (gridDim.x * blockDim.x) >> 6;
    const float dq = 1.f / 16000.f;
    for (int n = wv; n < N; n += nwv) {
        int beg = row_ptr[n], end = row_ptr[n + 1];
        float a0 = 0.f, a1 = 0.f, a2 = 0.f, a3 = 0.f;
#pragma unroll 2
        for (int e = beg + sg; e < end; e += 16) {
            unsigned u = wq_csr[e];
            int d = (int)(u & 0x1FFFFu);
            float w = (float)((int)(u >> 17) - 16384) * dq;
            h4 cv = *(const h4*)&cur[(size_t)d * 16 + c4 * 4];
            a0 += w * (float)cv[0];
            a1 += w * (float)cv[1];
            a2 += w * (float)cv[2];
            a3 += w * (float)cv[3];
        }
#pragma unroll
        for (int m = 4; m <= 32; m <<= 1) {
            a0 += __shfl_xor(a0, m);
            a1 += __shfl_xor(a1, m);
            a2 += __shfl_xor(a2, m);
            a3 += __shfl_xor(a3, m);
        }
        if (sg == 0) {
            float sc = scl[n];
            h4 iv = *(const h4*)&inith[(size_t)n * 16 + c4 * 4];
            float r0 = sc * a0 + (1.f - ALPHA_) * (float)iv[0];
            float r1 = sc * a1 + (1.f - ALPHA_) * (float)iv[1];
            float r2 = sc * a2 + (1.f - ALPHA_) * (float)iv[2];
            float r3 = sc * a3 + (1.f - ALPHA_) * (float)iv[3];
            if (LAST) {
                float4 st; st.x = r0; st.y = r1; st.z = r2; st.w = r3;
                *(float4*)&out32[(size_t)n * 16 + c4 * 4] = st;
            } else {
                h4 st;
                st[0] = (_Float16)r0; st[1] = (_Float16)r1;
                st[2] = (_Float16)r2; st[3] = (_Float16)r3;
                *(h4*)&out16[(size_t)n * 16 + c4 * 4] = st;
            }
        }
    }
}

extern "C" void kernel_launch(void* const* d_in, const int* in_sizes, int n_in,
                              void* d_out, int out_size, void* d_ws, size_t ws_size,
                              hipStream_t stream)
{
    const float* feat  = (const float*)d_in[0];
    const float* initl = (const float*)d_in[1];
    const float* W     = (const float*)d_in[2];
    const float* b     = (const float*)d_in[3];
    const float* gam   = (const float*)d_in[4];
    const float* bet   = (const float*)d_in[5];
    const float* ew0   = (const float*)d_in[6];
    const float* ew1   = (const float*)d_in[7];
    const float* ew2   = (const float*)d_in[8];
    const int* s0  = (const int*)d_in[9];
    const int* dd0 = (const int*)d_in[10];
    const int* s1  = (const int*)d_in[11];
    const int* dd1 = (const int*)d_in[12];
    const int* s2  = (const int*)d_in[13];
    const int* dd2 = (const int*)d_in[14];

    const int N = in_sizes[0] / DD;
    const int E = in_sizes[9];
    const int totE = 3 * E;
    const int NB = (N + 255) >> 8;
    float* out = (float*)d_out;

    char* ws = (char*)d_ws;
    size_t off = 0;
    auto alloc = [&](size_t bytes) -> void* {
        void* p = ws + off;
        off += (bytes + 255) & ~(size_t)255;
        return p;
    };
    unsigned*  hn8     = (unsigned*)alloc((size_t)N * DD);          // fp8 rows
    int*       gcnt    = (int*)alloc((size_t)(NB + 1) * 4);
    int*       bbase   = (int*)alloc((size_t)(NB + 1) * 4);
    int*       gcur    = (int*)alloc((size_t)(NB + 1) * 4);
    int*       row_ptr = (int*)alloc((size_t)(N + 1) * 4);
    unsigned*  stage   = (unsigned*)alloc((size_t)totE * 4);
    int*       dstc_csr= (int*)alloc((size_t)totE * 4);
    unsigned*  wq_csr  = (unsigned*)alloc((size_t)totE * 4);
    float*     scl     = (float*)alloc((size_t)N * 4);
    _Float16*  inith   = (_Float16*)alloc((size_t)N * CC * 2);
    _Float16*  curA    = (_Float16*)alloc((size_t)N * CC * 2);
    _Float16*  curB    = (_Float16*)alloc((size_t)N * CC * 2);

    // 1) feature transform (MFMA) -> fp8 normalized rows
    ft_mfma_kernel<<<512, 256, 0, stream>>>(feat, W, b, gam, bet, hn8, N);

    // 2) CSR build: bucket count -> scan -> partition -> per-bucket finalize
    hipMemsetAsync(gcnt, 0, (size_t)NB * 4, stream);
    bcount_kernel<<<NB, 256, 0, stream>>>(s0, s1, s2, gcnt, E, NB);
    bscan_kernel<<<1, 256, 0, stream>>>(gcnt, bbase, gcur, NB, totE);
    bpart_kernel<<<NB, 256, 0, stream>>>(s0, dd0, s1, dd1, s2, dd2,
                                         gcur, stage, E, NB);
    csrfin_kernel<<<NB, 256, 0, stream>>>(stage, bbase, row_ptr, dstc_csr, N, totE);

    // 3) fused edge weights (fp8 MFMA sims) -> packed 4B edges + scl
    const int wblk = (N * 64 + 255) / 256;
    node_sim_kernel<<<wblk, 256, 0, stream>>>((const unsigned char*)hn8,
                                              row_ptr, dstc_csr,
                                              ew0, ew1, ew2, wq_csr, scl, N);

    // 4) init -> f16, then 5 propagation layers (ping-pong, race-free)
    cvt_kernel<<<256, 256, 0, stream>>>(initl, inith, N * CC / 4);
    const _Float16* cs = inith;
    _Float16* bufs[2] = { curA, curB };
    for (int layer = 0; layer < 4; ++layer) {
        _Float16* dst = bufs[layer & 1];
        prop_kernel<false><<<wblk, 256, 0, stream>>>(row_ptr, wq_csr, scl,
                                                     cs, inith, nullptr, dst, N);
        cs = dst;
    }
    prop_kernel<true><<<wblk, 256, 0, stream>>>(row_ptr, wq_csr, scl,
                                                cs, inith, out, nullptr, N);
}